// Round 6
// baseline (423.330 us; speedup 1.0000x reference)
//
#include <hip/hip_runtime.h>

#define F    128
#define FQ   32    // F/4 (float4 per row)
#define FU   64    // uints per bf16 row
#define RPB  128   // rows per bucket
#define BSH  7     // log2(RPB)
#define TILE 2048  // edges per histogram tile (256 thr x 8)
#define SCAP 4096  // max edges per bucket section (mean 2046, +45 sigma)
#define LSTR 68    // LDS row stride in dwords (136 bf16): 16-B aligned, 2-way banks

typedef __attribute__((ext_vector_type(8))) short short8;   // MFMA A/B frag (8 bf16)
typedef __attribute__((ext_vector_type(4))) float f32x4;    // MFMA C/D frag
typedef __attribute__((ext_vector_type(4))) unsigned int u32x4;

// pack two fp32 -> two bf16 (RNE) in one uint (a = low = even feature)
__device__ __forceinline__ unsigned int f2bf2(float a, float b) {
    unsigned int ua = __float_as_uint(a);
    unsigned int ub = __float_as_uint(b);
    ua = (ua + 0x7fffu + ((ua >> 16) & 1u)) >> 16;
    ub = (ub + 0x7fffu + ((ub >> 16) & 1u)) >> 16;
    return ua | (ub << 16);
}
__device__ __forceinline__ unsigned short f2bf1(float a) {
    unsigned int ua = __float_as_uint(a);
    return (unsigned short)((ua + 0x7fffu + ((ua >> 16) & 1u)) >> 16);
}

__device__ __forceinline__ void fma8(float* acc, uint4 g, float wt) {
    unsigned int uu[4] = {g.x, g.y, g.z, g.w};
    #pragma unroll
    for (int j = 0; j < 4; ++j) {
        acc[2 * j]     = fmaf(wt, __uint_as_float(uu[j] << 16), acc[2 * j]);
        acc[2 * j + 1] = fmaf(wt, __uint_as_float(uu[j] & 0xffff0000u), acc[2 * j + 1]);
    }
}

// ---------------------------------------------------------------------------
// MFMA GEMM: H[n][f] = sum_k In[n][k] * W[k][f] -> packed bf16 [N][128].
// BN=false: X is fp32 [N][128].  BN=true: X is packed bf16 [N][64 uints],
// transformed relu(a[k]*x+c[k]) at staging; a,c computed per-thread from
// stats/gamma/beta (bnfinal kernel folded in here).
// ---------------------------------------------------------------------------
template <bool BN>
__global__ __launch_bounds__(256) void gemm_kernel(const void* __restrict__ Xv,
                                                   const float* __restrict__ W,
                                                   const float* __restrict__ stats,
                                                   const float* __restrict__ gamma,
                                                   const float* __restrict__ beta,
                                                   float invN,
                                                   unsigned int* __restrict__ Hb,
                                                   int nNodes) {
    __shared__ unsigned int XtU[64 * LSTR];    // bf16 pairs: Xt[node][k]
    __shared__ unsigned int WtU[128 * LSTR];   // bf16 pairs: Wt[feat][k]

    const int tid = threadIdx.x;
    const int bn0 = blockIdx.x * 64;

    // ---- stage W transposed ----
    {
        int f = tid >> 1;
        int kh = (tid & 1) * 64;
        #pragma unroll
        for (int k8 = 0; k8 < 8; ++k8) {
            int k0 = kh + k8 * 8;
            float v[8];
            #pragma unroll
            for (int i = 0; i < 8; ++i) v[i] = W[(size_t)(k0 + i) * F + f];
            uint4 pk;
            pk.x = f2bf2(v[0], v[1]);
            pk.y = f2bf2(v[2], v[3]);
            pk.z = f2bf2(v[4], v[5]);
            pk.w = f2bf2(v[6], v[7]);
            *(uint4*)&WtU[f * LSTR + k0 / 2] = pk;
        }
    }
    // ---- stage X tile as bf16, optional BN+ReLU (BN coeffs computed here) ----
    {
        const int kq = tid & 31;               // (tid + it*256) & 31 is constant
        float4 a4, c4;
        if (BN) {
            float4 s  = ((const float4*)stats)[kq];
            float4 sq = ((const float4*)(stats + 128))[kq];
            float4 g4 = ((const float4*)gamma)[kq];
            float4 b4 = ((const float4*)beta)[kq];
            float m;
            m = s.x * invN; a4.x = g4.x * rsqrtf(sq.x * invN - m * m + 1e-5f); c4.x = b4.x - m * a4.x;
            m = s.y * invN; a4.y = g4.y * rsqrtf(sq.y * invN - m * m + 1e-5f); c4.y = b4.y - m * a4.y;
            m = s.z * invN; a4.z = g4.z * rsqrtf(sq.z * invN - m * m + 1e-5f); c4.z = b4.z - m * a4.z;
            m = s.w * invN; a4.w = g4.w * rsqrtf(sq.w * invN - m * m + 1e-5f); c4.w = b4.w - m * a4.w;
        }
        #pragma unroll
        for (int it = 0; it < 8; ++it) {
            int i = tid + it * 256;            // 0..2047
            int n = i >> 5;                    // node 0..63
            int node = bn0 + n;
            uint2 pk = make_uint2(0u, 0u);
            if (BN) {
                uint2 raw = make_uint2(0u, 0u);
                if (node < nNodes) raw = ((const uint2*)Xv)[(size_t)node * 32 + kq];
                float4 v;
                v.x = __uint_as_float(raw.x << 16);
                v.y = __uint_as_float(raw.x & 0xffff0000u);
                v.z = __uint_as_float(raw.y << 16);
                v.w = __uint_as_float(raw.y & 0xffff0000u);
                v.x = fmaxf(fmaf(a4.x, v.x, c4.x), 0.f);
                v.y = fmaxf(fmaf(a4.y, v.y, c4.y), 0.f);
                v.z = fmaxf(fmaf(a4.z, v.z, c4.z), 0.f);
                v.w = fmaxf(fmaf(a4.w, v.w, c4.w), 0.f);
                pk = make_uint2(f2bf2(v.x, v.y), f2bf2(v.z, v.w));
            } else {
                float4 v = make_float4(0.f, 0.f, 0.f, 0.f);
                if (node < nNodes) v = ((const float4*)Xv)[(size_t)node * FQ + kq];
                pk = make_uint2(f2bf2(v.x, v.y), f2bf2(v.z, v.w));
            }
            *(uint2*)&XtU[n * LSTR + kq * 2] = pk;
        }
    }
    __syncthreads();

    // ---- MFMA compute ----
    const int l = tid & 63;
    const int wv = tid >> 6;
    const int quad = l >> 4, lo = l & 15;
    const int fb = wv * 32;

    f32x4 acc[4][2];
    #pragma unroll
    for (int nt = 0; nt < 4; ++nt)
        #pragma unroll
        for (int ft = 0; ft < 2; ++ft) acc[nt][ft] = (f32x4){0.f, 0.f, 0.f, 0.f};

    #pragma unroll
    for (int kc = 0; kc < 4; ++kc) {
        int koff = kc * 16 + quad * 4;
        short8 a[4], b[2];
        #pragma unroll
        for (int nt = 0; nt < 4; ++nt)
            a[nt] = *(const short8*)&XtU[(nt * 16 + lo) * LSTR + koff];
        #pragma unroll
        for (int ft = 0; ft < 2; ++ft)
            b[ft] = *(const short8*)&WtU[(fb + ft * 16 + lo) * LSTR + koff];
        #pragma unroll
        for (int nt = 0; nt < 4; ++nt)
            #pragma unroll
            for (int ft = 0; ft < 2; ++ft)
                acc[nt][ft] = __builtin_amdgcn_mfma_f32_16x16x32_bf16(
                    a[nt], b[ft], acc[nt][ft], 0, 0, 0);
    }

    // ---- epilogue: bf16 store (D: col=lane&15, row=quad*4+reg) ----
    unsigned short* Hs = (unsigned short*)Hb;
    #pragma unroll
    for (int nt = 0; nt < 4; ++nt) {
        #pragma unroll
        for (int reg = 0; reg < 4; ++reg) {
            int node = bn0 + nt * 16 + quad * 4 + reg;
            if (node < nNodes) {
                #pragma unroll
                for (int ft = 0; ft < 2; ++ft)
                    Hs[(size_t)node * F + fb + ft * 16 + lo] = f2bf1(acc[nt][ft][reg]);
            }
        }
    }
}

// ---------------------------------------------------------------------------
// CSR build via deterministic bucket sort — NO returning global atomics.
// ---------------------------------------------------------------------------
__global__ __launch_bounds__(256) void histo_kernel(const int* __restrict__ row,
                                                    int* __restrict__ hist,
                                                    int NB, int E) {
    __shared__ int h[1024];
    int t = threadIdx.x;
    for (int i = t; i < NB; i += 256) h[i] = 0;
    __syncthreads();
    int base = blockIdx.x * TILE + t * 8;
    if (base + 7 < E) {
        int4 a = ((const int4*)row)[(base >> 2) + 0];
        int4 b = ((const int4*)row)[(base >> 2) + 1];
        atomicAdd(&h[a.x >> BSH], 1); atomicAdd(&h[a.y >> BSH], 1);
        atomicAdd(&h[a.z >> BSH], 1); atomicAdd(&h[a.w >> BSH], 1);
        atomicAdd(&h[b.x >> BSH], 1); atomicAdd(&h[b.y >> BSH], 1);
        atomicAdd(&h[b.z >> BSH], 1); atomicAdd(&h[b.w >> BSH], 1);
    } else {
        for (int j = 0; j < 8; ++j)
            if (base + j < E) atomicAdd(&h[row[base + j] >> BSH], 1);
    }
    __syncthreads();
    for (int i = t; i < NB; i += 256) hist[(size_t)blockIdx.x * NB + i] = h[i];
}

__global__ __launch_bounds__(256) void btot_kernel(const int* __restrict__ hist,
                                                   int* __restrict__ total,
                                                   int nT, int NB) {
    int b = blockIdx.x;
    int s = 0;
    for (int t = threadIdx.x; t < nT; t += 256) s += hist[(size_t)t * NB + b];
    __shared__ int red[256];
    red[threadIdx.x] = s;
    __syncthreads();
    for (int o = 128; o > 0; o >>= 1) {
        if (threadIdx.x < o) red[threadIdx.x] += red[threadIdx.x + o];
        __syncthreads();
    }
    if (threadIdx.x == 0) total[b] = red[0];
}

__global__ __launch_bounds__(1024) void bstart_kernel(const int* __restrict__ total,
                                                      int* __restrict__ start,
                                                      int NB, int E) {
    __shared__ int sh[1024];
    int t = threadIdx.x;
    int v = (t < NB) ? total[t] : 0;
    sh[t] = v;
    __syncthreads();
    #pragma unroll
    for (int o = 1; o < 1024; o <<= 1) {
        int add = (t >= o) ? sh[t - o] : 0;
        __syncthreads();
        sh[t] += add;
        __syncthreads();
    }
    if (t < NB) start[t] = sh[t] - v;
    if (t == 0) start[NB] = E;
}

__global__ __launch_bounds__(1024) void boff_kernel(const int* __restrict__ hist,
                                                    const int* __restrict__ start,
                                                    int* __restrict__ off,
                                                    int nT, int NB) {
    __shared__ int sh[1024];
    int b = blockIdx.x, t = threadIdx.x;
    int v = (t < nT) ? hist[(size_t)t * NB + b] : 0;
    sh[t] = v;
    __syncthreads();
    #pragma unroll
    for (int o = 1; o < 1024; o <<= 1) {
        int add = (t >= o) ? sh[t - o] : 0;
        __syncthreads();
        sh[t] += add;
        __syncthreads();
    }
    if (t < nT) off[(size_t)b * nT + t] = start[b] + sh[t] - v;
}

__global__ __launch_bounds__(256) void bplace_kernel(const int* __restrict__ row,
                                                     const int* __restrict__ col,
                                                     const float* __restrict__ w,
                                                     const int* __restrict__ off,
                                                     int2* __restrict__ tmp,
                                                     int nT, int NB, int E) {
    __shared__ int h[1024];
    int t = threadIdx.x, tile = blockIdx.x;
    for (int i = t; i < NB; i += 256) h[i] = 0;
    __syncthreads();
    int base = tile * TILE + t * 8;
    int r[8], c[8];
    float ww[8];
    int nv = 0;
    if (base + 7 < E) {
        int4 ra = ((const int4*)row)[(base >> 2) + 0];
        int4 rb = ((const int4*)row)[(base >> 2) + 1];
        int4 ca = ((const int4*)col)[(base >> 2) + 0];
        int4 cb = ((const int4*)col)[(base >> 2) + 1];
        float4 wa = ((const float4*)w)[(base >> 2) + 0];
        float4 wb = ((const float4*)w)[(base >> 2) + 1];
        r[0] = ra.x; r[1] = ra.y; r[2] = ra.z; r[3] = ra.w;
        r[4] = rb.x; r[5] = rb.y; r[6] = rb.z; r[7] = rb.w;
        c[0] = ca.x; c[1] = ca.y; c[2] = ca.z; c[3] = ca.w;
        c[4] = cb.x; c[5] = cb.y; c[6] = cb.z; c[7] = cb.w;
        ww[0] = wa.x; ww[1] = wa.y; ww[2] = wa.z; ww[3] = wa.w;
        ww[4] = wb.x; ww[5] = wb.y; ww[6] = wb.z; ww[7] = wb.w;
        nv = 8;
    } else {
        for (int j = 0; j < 8; ++j)
            if (base + j < E) { r[nv] = row[base + j]; c[nv] = col[base + j];
                                ww[nv] = w[base + j]; ++nv; }
    }
    #pragma unroll 8
    for (int j = 0; j < 8; ++j) {
        if (j >= nv) break;
        int b = r[j] >> BSH;
        int rank = atomicAdd(&h[b], 1);
        int pos = off[(size_t)b * nT + tile] + rank;
        tmp[pos] = make_int2(((r[j] & (RPB - 1)) << 25) | c[j], __float_as_int(ww[j]));
    }
}

__global__ __launch_bounds__(256) void bsort_kernel(const int2* __restrict__ tmp,
                                                    const int* __restrict__ start,
                                                    int2* __restrict__ pairs,
                                                    int* __restrict__ rowptr,
                                                    int N, int NB, int E) {
    __shared__ int cntB[RPB];
    __shared__ int cntS[RPB];
    __shared__ int sc[RPB];
    __shared__ int2 outP[SCAP];
    int b = blockIdx.x, t = threadIdx.x;
    int s0 = start[b], s1 = start[b + 1];
    int len = s1 - s0;
    if (len > SCAP) len = SCAP;

    if (t < RPB) cntB[t] = 0;
    __syncthreads();

    int2 p[16];
    int np = 0;
    #pragma unroll
    for (int k = 0; k < 16; ++k) {
        int i = t + k * 256;
        if (i < len) { p[k] = tmp[s0 + i]; ++np; }
    }
    #pragma unroll
    for (int k = 0; k < 16; ++k) {
        if (k >= np) break;
        atomicAdd(&cntB[((unsigned)p[k].x) >> 25], 1);
    }
    __syncthreads();
    int val = (t < RPB) ? cntB[t] : 0;
    if (t < RPB) sc[t] = val;
    __syncthreads();
    #pragma unroll
    for (int o = 1; o < RPB; o <<= 1) {
        int add = (t < RPB && t >= o) ? sc[t - o] : 0;
        __syncthreads();
        if (t < RPB) sc[t] += add;
        __syncthreads();
    }
    if (t < RPB) { int ex = sc[t] - val; cntB[t] = ex; cntS[t] = ex; }
    __syncthreads();
    #pragma unroll
    for (int k = 0; k < 16; ++k) {
        if (k >= np) break;
        int rl = ((unsigned)p[k].x) >> 25;
        int lr = atomicAdd(&cntB[rl], 1);
        outP[lr] = make_int2(p[k].x & 0x1ffffff, p[k].y);
    }
    __syncthreads();
    for (int i = t; i < len; i += 256) pairs[s0 + i] = outP[i];
    int r0 = b * RPB;
    if (t < RPB && r0 + t < N) rowptr[r0 + t] = s0 + cntS[t];
    if (b == NB - 1 && t == 0) rowptr[N] = E;
}

// ---------------------------------------------------------------------------
// CSR SpMM v6: TWO rows per wave, statically interleaved -> 8 independent
// 256-B gathers in flight per lane (MLP-8, was 4).  Each 16-edge batch is
// fully PREDICATED (clamped pairs index, col=0/wt=0 for invalid lanes), so
// a row with deg<=16 finishes in ONE MLP-4 round — the old remainder loops
// (4 edges/round, MLP-1, up to 3 dependent rounds) are gone.
// Lane layout per row: 4 edge-subgroups (g) x 16 lanes (q); uint4 = 8 feats.
// fp32 output (final) is NT-stored (never re-read); bf16 output (buf1) is
// cached — it IS re-read by bnstats + gemm<true> (R5 lesson).
// ---------------------------------------------------------------------------
template <bool BF16OUT>
__global__ __launch_bounds__(256) void spmm_csr_kernel(const int* __restrict__ rowptr,
                                                       const int2* __restrict__ pairs,
                                                       const unsigned int* __restrict__ Hb,
                                                       const float* __restrict__ bias,
                                                       void* __restrict__ outv,
                                                       int N, int E) {
    const int w  = threadIdx.x >> 6;
    const int rA = blockIdx.x * 8 + w * 2;
    const int rB = rA + 1;
    const int l  = threadIdx.x & 63;
    const int g  = l >> 4, q = l & 15;         // edge subgroup, 8-feat chunk
    const uint4* H4 = (const uint4*)Hb;        // row = 16 uint4
    const int Em1 = E - 1;

    int a0 = 0, aEnd = 0, b0 = 0, bEnd = 0;
    if (rA < N) { a0 = rowptr[rA]; aEnd = rowptr[rA + 1]; }
    if (rB < N) { b0 = rowptr[rB]; bEnd = rowptr[rB + 1]; }

    float accA[8], accB[8];
    #pragma unroll
    for (int j = 0; j < 8; ++j) { accA[j] = 0.f; accB[j] = 0.f; }

    const int nIt = max((aEnd - a0 + 15) >> 4, (bEnd - b0 + 15) >> 4);

    for (int t = 0; t < nIt; ++t) {
        const int baseA = a0 + t * 16 + g;
        const int baseB = b0 + t * 16 + g;
        int   cA[4], cB[4];
        float wA[4], wB[4];
        // 8 independent pairs loads (predicated via clamp+mask)
        #pragma unroll
        for (int k = 0; k < 4; ++k) {
            int  eA = baseA + 4 * k;
            int  eB = baseB + 4 * k;
            bool vA = eA < aEnd;
            bool vB = eB < bEnd;
            int2 pA = pairs[min(eA, Em1)];
            int2 pB = pairs[min(eB, Em1)];
            cA[k] = vA ? pA.x : 0;  wA[k] = vA ? __int_as_float(pA.y) : 0.f;
            cB[k] = vB ? pB.x : 0;  wB[k] = vB ? __int_as_float(pB.y) : 0.f;
        }
        // 8 independent gathers in flight
        uint4 gA[4], gB[4];
        #pragma unroll
        for (int k = 0; k < 4; ++k) {
            gA[k] = H4[(size_t)cA[k] * 16 + q];
            gB[k] = H4[(size_t)cB[k] * 16 + q];
        }
        #pragma unroll
        for (int k = 0; k < 4; ++k) {
            fma8(accA, gA[k], wA[k]);
            fma8(accB, gB[k], wB[k]);
        }
    }

    // reduce the 4 edge-subgroups (lanes q, q+16, q+32, q+48)
    #pragma unroll
    for (int j = 0; j < 8; ++j) {
        accA[j] += __shfl_xor(accA[j], 16, 64);
        accA[j] += __shfl_xor(accA[j], 32, 64);
        accB[j] += __shfl_xor(accB[j], 16, 64);
        accB[j] += __shfl_xor(accB[j], 32, 64);
    }

    if (g == 0) {
        float4 bs0 = make_float4(0.f, 0.f, 0.f, 0.f), bs1 = bs0;
        if (!BF16OUT && bias) {
            bs0 = ((const float4*)bias)[q * 2];
            bs1 = ((const float4*)bias)[q * 2 + 1];
        }
        #pragma unroll
        for (int sel = 0; sel < 2; ++sel) {
            const int r = rA + sel;
            const float* acc = sel ? accB : accA;
            if (r < N) {
                if (BF16OUT) {
                    u32x4 pk;
                    pk.x = f2bf2(acc[0], acc[1]);
                    pk.y = f2bf2(acc[2], acc[3]);
                    pk.z = f2bf2(acc[4], acc[5]);
                    pk.w = f2bf2(acc[6], acc[7]);
                    ((u32x4*)outv)[(size_t)r * 16 + q] = pk;   // cached: re-read later
                } else {
                    f32x4 v0 = (f32x4){acc[0] + bs0.x, acc[1] + bs0.y,
                                       acc[2] + bs0.z, acc[3] + bs0.w};
                    f32x4 v1 = (f32x4){acc[4] + bs1.x, acc[5] + bs1.y,
                                       acc[6] + bs1.z, acc[7] + bs1.w};
                    f32x4* O = (f32x4*)outv;
                    __builtin_nontemporal_store(v0, &O[(size_t)r * 32 + q * 2]);
                    __builtin_nontemporal_store(v1, &O[(size_t)r * 32 + q * 2 + 1]);
                }
            }
        }
    }
}

// ---------------------------------------------------------------------------
// BN batch statistics over packed-bf16 input: per-feature sum and sumsq.
// ---------------------------------------------------------------------------
__global__ __launch_bounds__(256) void bnstats_kernel(const unsigned int* __restrict__ Hu,
                                                      float* __restrict__ sums,
                                                      int nNodes) {
    int u = threadIdx.x & 63;   // uint index: feats 2u, 2u+1
    int g = threadIdx.x >> 6;   // 0..3
    int stride = gridDim.x * 4;
    float s0 = 0.f, s1 = 0.f, q0 = 0.f, q1 = 0.f;
    for (int n = blockIdx.x * 4 + g; n < nNodes; n += stride) {
        unsigned int v = Hu[(size_t)n * FU + u];
        float a = __uint_as_float(v << 16);
        float b = __uint_as_float(v & 0xffff0000u);
        s0 += a; s1 += b;
        q0 = fmaf(a, a, q0); q1 = fmaf(b, b, q1);
    }
    __shared__ float4 red[256];
    red[threadIdx.x] = make_float4(s0, s1, q0, q1);
    __syncthreads();
    if (g == 0) {
        float4 r0 = red[u], r1 = red[64 + u], r2 = red[128 + u], r3 = red[192 + u];
        atomicAdd(&sums[2 * u],           r0.x + r1.x + r2.x + r3.x);
        atomicAdd(&sums[2 * u + 1],       r0.y + r1.y + r2.y + r3.y);
        atomicAdd(&sums[128 + 2 * u],     r0.z + r1.z + r2.z + r3.z);
        atomicAdd(&sums[128 + 2 * u + 1], r0.w + r1.w + r2.w + r3.w);
    }
}

extern "C" void kernel_launch(void* const* d_in, const int* in_sizes, int n_in,
                              void* d_out, int out_size, void* d_ws, size_t ws_size,
                              hipStream_t stream) {
    const float* x    = (const float*)d_in[0];
    const int*   erow = (const int*)d_in[1];
    const int*   ecol = (const int*)d_in[2];
    const float* ew   = (const float*)d_in[3];
    const float* W1   = (const float*)d_in[4];
    // d_in[5] = b1: unused — cancels exactly under BatchNorm mean subtraction.
    const float* W2   = (const float*)d_in[6];
    const float* b2   = (const float*)d_in[7];
    const float* gmm  = (const float*)d_in[8];
    const float* beta = (const float*)d_in[9];
    float* out = (float*)d_out;

    const int N = in_sizes[0] / F;   // 100000
    const int E = in_sizes[1];       // 1600000

    const int NB = (N + RPB - 1) / RPB;     // 782
    const int nT = (E + TILE - 1) / TILE;   // 782

    // ---- workspace carve-up ----
    unsigned int* buf1   = (unsigned int*)d_ws;                   // N*FU bf16 (h1)
    unsigned int* Hb     = buf1 + (size_t)N * FU;                 // N*FU bf16 (h0/h2)
    float*        stats  = (float*)(Hb + (size_t)N * FU);         // 256
    int*          rowptr = (int*)(stats + 256);                   // N+2
    int*          start  = rowptr + N + 2;                        // 1028
    int*          total  = start + 1028;                          // 1024
    int*          hist   = total + 1024;                          // nT*NB
    int*          off    = hist + (size_t)nT * NB;                // NB*nT
    int2*         tmp    = (int2*)(off + (size_t)NB * nT);        // E
    int2*         pairs  = tmp + E;                               // E

    const int gemmGrid = (N + 63) / 64;
    const int spmmGrid = (N + 7) / 8;

    hipMemsetAsync(stats, 0, 256 * sizeof(float), stream);

    // ---- build CSR: deterministic bucket sort, shared by both layers ----
    histo_kernel<<<nT, 256, 0, stream>>>(erow, hist, NB, E);
    btot_kernel<<<NB, 256, 0, stream>>>(hist, total, nT, NB);
    bstart_kernel<<<1, 1024, 0, stream>>>(total, start, NB, E);
    boff_kernel<<<NB, 1024, 0, stream>>>(hist, start, off, nT, NB);
    bplace_kernel<<<nT, 256, 0, stream>>>(erow, ecol, ew, off, tmp, nT, NB, E);
    bsort_kernel<<<NB, 256, 0, stream>>>(tmp, start, pairs, rowptr, N, NB, E);

    // Layer 1: Hb = bf16(x @ W1) ; buf1 = bf16(A @ Hb)
    gemm_kernel<false><<<gemmGrid, 256, 0, stream>>>(x, W1, nullptr, nullptr,
                                                     nullptr, 0.f, Hb, N);
    spmm_csr_kernel<true><<<spmmGrid, 256, 0, stream>>>(rowptr, pairs, Hb,
                                                        nullptr, buf1, N, E);
    // BN stats (BN-fold happens inside gemm<true>)
    bnstats_kernel<<<400, 256, 0, stream>>>(buf1, stats, N);
    // Layer 2: Hb = bf16(relu(bn(buf1)) @ W2) ; out = A @ Hb + b2 (fp32)
    gemm_kernel<true><<<gemmGrid, 256, 0, stream>>>(buf1, W2, stats, gmm, beta,
                                                    1.0f / (float)N, Hb, N);
    spmm_csr_kernel<false><<<spmmGrid, 256, 0, stream>>>(rowptr, pairs, Hb,
                                                         b2, out, N, E);
}

// Round 7
// 397.214 us; speedup vs baseline: 1.0657x; 1.0657x over previous
//
#include <hip/hip_runtime.h>

#define F    128
#define FQ   32    // F/4 (float4 per row)
#define FU   64    // uints per bf16 row
#define RPB  128   // rows per bucket
#define BSH  7     // log2(RPB)
#define TILE 2048  // edges per histogram tile (256 thr x 8)
#define SCAP 4096  // max edges per bucket section (mean 2046, +45 sigma)
#define LSTR 68    // LDS row stride in dwords (136 bf16): 16-B aligned, 2-way banks

typedef __attribute__((ext_vector_type(8))) short short8;   // MFMA A/B frag (8 bf16)
typedef __attribute__((ext_vector_type(4))) float f32x4;    // MFMA C/D frag
typedef __attribute__((ext_vector_type(4))) unsigned int u32x4;

// pack two fp32 -> two bf16 (RNE) in one uint (a = low = even feature)
__device__ __forceinline__ unsigned int f2bf2(float a, float b) {
    unsigned int ua = __float_as_uint(a);
    unsigned int ub = __float_as_uint(b);
    ua = (ua + 0x7fffu + ((ua >> 16) & 1u)) >> 16;
    ub = (ub + 0x7fffu + ((ub >> 16) & 1u)) >> 16;
    return ua | (ub << 16);
}
__device__ __forceinline__ unsigned short f2bf1(float a) {
    unsigned int ua = __float_as_uint(a);
    return (unsigned short)((ua + 0x7fffu + ((ua >> 16) & 1u)) >> 16);
}

// ---------------------------------------------------------------------------
// W pre-pack: fp32 W[k][f] -> bf16 pairs Wt[f][k] (64 uints per f-row).
// Runs ONCE per launch (2 blocks); removes 2x1563 redundant per-block
// transpose+convert stagings (~25M VALU converts) from the gemm kernels.
// ---------------------------------------------------------------------------
__global__ __launch_bounds__(256) void wconv_kernel(const float* __restrict__ W1,
                                                    const float* __restrict__ W2,
                                                    unsigned int* __restrict__ Wt1,
                                                    unsigned int* __restrict__ Wt2) {
    const float* W = blockIdx.x ? W2 : W1;
    unsigned int* Wt = blockIdx.x ? Wt2 : Wt1;
    int f = threadIdx.x & 127;
    int kh = (threadIdx.x >> 7) * 64;
    #pragma unroll
    for (int k8 = 0; k8 < 8; ++k8) {
        int k0 = kh + k8 * 8;
        float v[8];
        #pragma unroll
        for (int i = 0; i < 8; ++i) v[i] = W[(size_t)(k0 + i) * F + f];
        uint4 pk;
        pk.x = f2bf2(v[0], v[1]);
        pk.y = f2bf2(v[2], v[3]);
        pk.z = f2bf2(v[4], v[5]);
        pk.w = f2bf2(v[6], v[7]);
        *(uint4*)&Wt[f * 64 + k0 / 2] = pk;
    }
}

// ---------------------------------------------------------------------------
// MFMA GEMM: H[n][f] = sum_k In[n][k] * W[k][f] -> packed bf16 [N][128].
// W arrives PRE-PACKED bf16 [f][k] (wconv) -> staging is pure coalesced copy.
// BN=false: X is fp32 [N][128].  BN=true: X is packed bf16 [N][64 uints],
// transformed relu(a[k]*x+c[k]) at staging; a,c computed per-thread from
// stats/gamma/beta (bnfinal kernel folded in here).
// ---------------------------------------------------------------------------
template <bool BN>
__global__ __launch_bounds__(256) void gemm_kernel(const void* __restrict__ Xv,
                                                   const unsigned int* __restrict__ Wt,
                                                   const float* __restrict__ stats,
                                                   const float* __restrict__ gamma,
                                                   const float* __restrict__ beta,
                                                   float invN,
                                                   unsigned int* __restrict__ Hb,
                                                   int nNodes) {
    __shared__ unsigned int XtU[64 * LSTR];    // bf16 pairs: Xt[node][k]
    __shared__ unsigned int WtU[128 * LSTR];   // bf16 pairs: Wt[feat][k]

    const int tid = threadIdx.x;
    const int bn0 = blockIdx.x * 64;

    // ---- stage W (coalesced uint4 copy of pre-packed bf16) ----
    {
        int f = tid >> 1;
        int kh = (tid & 1) * 32;               // uint offset within 64-uint row
        const uint4* Wg4 = (const uint4*)Wt;   // f-row = 16 uint4
        #pragma unroll
        for (int j = 0; j < 8; ++j) {
            uint4 pk = Wg4[f * 16 + (kh >> 2) + j];
            *(uint4*)&WtU[f * LSTR + kh + j * 4] = pk;
        }
    }
    // ---- stage X tile as bf16, optional BN+ReLU (BN coeffs computed here) ----
    {
        const int kq = tid & 31;               // (tid + it*256) & 31 is constant
        float4 a4, c4;
        if (BN) {
            float4 s  = ((const float4*)stats)[kq];
            float4 sq = ((const float4*)(stats + 128))[kq];
            float4 g4 = ((const float4*)gamma)[kq];
            float4 b4 = ((const float4*)beta)[kq];
            float m;
            m = s.x * invN; a4.x = g4.x * rsqrtf(sq.x * invN - m * m + 1e-5f); c4.x = b4.x - m * a4.x;
            m = s.y * invN; a4.y = g4.y * rsqrtf(sq.y * invN - m * m + 1e-5f); c4.y = b4.y - m * a4.y;
            m = s.z * invN; a4.z = g4.z * rsqrtf(sq.z * invN - m * m + 1e-5f); c4.z = b4.z - m * a4.z;
            m = s.w * invN; a4.w = g4.w * rsqrtf(sq.w * invN - m * m + 1e-5f); c4.w = b4.w - m * a4.w;
        }
        #pragma unroll
        for (int it = 0; it < 8; ++it) {
            int i = tid + it * 256;            // 0..2047
            int n = i >> 5;                    // node 0..63
            int node = bn0 + n;
            uint2 pk = make_uint2(0u, 0u);
            if (BN) {
                uint2 raw = make_uint2(0u, 0u);
                if (node < nNodes) raw = ((const uint2*)Xv)[(size_t)node * 32 + kq];
                float4 v;
                v.x = __uint_as_float(raw.x << 16);
                v.y = __uint_as_float(raw.x & 0xffff0000u);
                v.z = __uint_as_float(raw.y << 16);
                v.w = __uint_as_float(raw.y & 0xffff0000u);
                v.x = fmaxf(fmaf(a4.x, v.x, c4.x), 0.f);
                v.y = fmaxf(fmaf(a4.y, v.y, c4.y), 0.f);
                v.z = fmaxf(fmaf(a4.z, v.z, c4.z), 0.f);
                v.w = fmaxf(fmaf(a4.w, v.w, c4.w), 0.f);
                pk = make_uint2(f2bf2(v.x, v.y), f2bf2(v.z, v.w));
            } else {
                float4 v = make_float4(0.f, 0.f, 0.f, 0.f);
                if (node < nNodes) v = ((const float4*)Xv)[(size_t)node * FQ + kq];
                pk = make_uint2(f2bf2(v.x, v.y), f2bf2(v.z, v.w));
            }
            *(uint2*)&XtU[n * LSTR + kq * 2] = pk;
        }
    }
    __syncthreads();

    // ---- MFMA compute ----
    const int l = tid & 63;
    const int wv = tid >> 6;
    const int quad = l >> 4, lo = l & 15;
    const int fb = wv * 32;

    f32x4 acc[4][2];
    #pragma unroll
    for (int nt = 0; nt < 4; ++nt)
        #pragma unroll
        for (int ft = 0; ft < 2; ++ft) acc[nt][ft] = (f32x4){0.f, 0.f, 0.f, 0.f};

    #pragma unroll
    for (int kc = 0; kc < 4; ++kc) {
        int koff = kc * 16 + quad * 4;
        short8 a[4], b[2];
        #pragma unroll
        for (int nt = 0; nt < 4; ++nt)
            a[nt] = *(const short8*)&XtU[(nt * 16 + lo) * LSTR + koff];
        #pragma unroll
        for (int ft = 0; ft < 2; ++ft)
            b[ft] = *(const short8*)&WtU[(fb + ft * 16 + lo) * LSTR + koff];
        #pragma unroll
        for (int nt = 0; nt < 4; ++nt)
            #pragma unroll
            for (int ft = 0; ft < 2; ++ft)
                acc[nt][ft] = __builtin_amdgcn_mfma_f32_16x16x32_bf16(
                    a[nt], b[ft], acc[nt][ft], 0, 0, 0);
    }

    // ---- epilogue: bf16 store (D: col=lane&15, row=quad*4+reg) ----
    unsigned short* Hs = (unsigned short*)Hb;
    #pragma unroll
    for (int nt = 0; nt < 4; ++nt) {
        #pragma unroll
        for (int reg = 0; reg < 4; ++reg) {
            int node = bn0 + nt * 16 + quad * 4 + reg;
            if (node < nNodes) {
                #pragma unroll
                for (int ft = 0; ft < 2; ++ft)
                    Hs[(size_t)node * F + fb + ft * 16 + lo] = f2bf1(acc[nt][ft][reg]);
            }
        }
    }
}

// ---------------------------------------------------------------------------
// CSR build via deterministic bucket sort — NO returning global atomics.
// ---------------------------------------------------------------------------
__global__ __launch_bounds__(256) void histo_kernel(const int* __restrict__ row,
                                                    int* __restrict__ hist,
                                                    int NB, int E) {
    __shared__ int h[1024];
    int t = threadIdx.x;
    for (int i = t; i < NB; i += 256) h[i] = 0;
    __syncthreads();
    int base = blockIdx.x * TILE + t * 8;
    if (base + 7 < E) {
        int4 a = ((const int4*)row)[(base >> 2) + 0];
        int4 b = ((const int4*)row)[(base >> 2) + 1];
        atomicAdd(&h[a.x >> BSH], 1); atomicAdd(&h[a.y >> BSH], 1);
        atomicAdd(&h[a.z >> BSH], 1); atomicAdd(&h[a.w >> BSH], 1);
        atomicAdd(&h[b.x >> BSH], 1); atomicAdd(&h[b.y >> BSH], 1);
        atomicAdd(&h[b.z >> BSH], 1); atomicAdd(&h[b.w >> BSH], 1);
    } else {
        for (int j = 0; j < 8; ++j)
            if (base + j < E) atomicAdd(&h[row[base + j] >> BSH], 1);
    }
    __syncthreads();
    for (int i = t; i < NB; i += 256) hist[(size_t)blockIdx.x * NB + i] = h[i];
}

__global__ __launch_bounds__(256) void btot_kernel(const int* __restrict__ hist,
                                                   int* __restrict__ total,
                                                   int nT, int NB) {
    int b = blockIdx.x;
    int s = 0;
    for (int t = threadIdx.x; t < nT; t += 256) s += hist[(size_t)t * NB + b];
    __shared__ int red[256];
    red[threadIdx.x] = s;
    __syncthreads();
    for (int o = 128; o > 0; o >>= 1) {
        if (threadIdx.x < o) red[threadIdx.x] += red[threadIdx.x + o];
        __syncthreads();
    }
    if (threadIdx.x == 0) total[b] = red[0];
}

__global__ __launch_bounds__(1024) void bstart_kernel(const int* __restrict__ total,
                                                      int* __restrict__ start,
                                                      int NB, int E) {
    __shared__ int sh[1024];
    int t = threadIdx.x;
    int v = (t < NB) ? total[t] : 0;
    sh[t] = v;
    __syncthreads();
    #pragma unroll
    for (int o = 1; o < 1024; o <<= 1) {
        int add = (t >= o) ? sh[t - o] : 0;
        __syncthreads();
        sh[t] += add;
        __syncthreads();
    }
    if (t < NB) start[t] = sh[t] - v;
    if (t == 0) start[NB] = E;
}

__global__ __launch_bounds__(1024) void boff_kernel(const int* __restrict__ hist,
                                                    const int* __restrict__ start,
                                                    int* __restrict__ off,
                                                    int nT, int NB) {
    __shared__ int sh[1024];
    int b = blockIdx.x, t = threadIdx.x;
    int v = (t < nT) ? hist[(size_t)t * NB + b] : 0;
    sh[t] = v;
    __syncthreads();
    #pragma unroll
    for (int o = 1; o < 1024; o <<= 1) {
        int add = (t >= o) ? sh[t - o] : 0;
        __syncthreads();
        sh[t] += add;
        __syncthreads();
    }
    if (t < nT) off[(size_t)b * nT + t] = start[b] + sh[t] - v;
}

__global__ __launch_bounds__(256) void bplace_kernel(const int* __restrict__ row,
                                                     const int* __restrict__ col,
                                                     const float* __restrict__ w,
                                                     const int* __restrict__ off,
                                                     int2* __restrict__ tmp,
                                                     int nT, int NB, int E) {
    __shared__ int h[1024];
    int t = threadIdx.x, tile = blockIdx.x;
    for (int i = t; i < NB; i += 256) h[i] = 0;
    __syncthreads();
    int base = tile * TILE + t * 8;
    int r[8], c[8];
    float ww[8];
    int nv = 0;
    if (base + 7 < E) {
        int4 ra = ((const int4*)row)[(base >> 2) + 0];
        int4 rb = ((const int4*)row)[(base >> 2) + 1];
        int4 ca = ((const int4*)col)[(base >> 2) + 0];
        int4 cb = ((const int4*)col)[(base >> 2) + 1];
        float4 wa = ((const float4*)w)[(base >> 2) + 0];
        float4 wb = ((const float4*)w)[(base >> 2) + 1];
        r[0] = ra.x; r[1] = ra.y; r[2] = ra.z; r[3] = ra.w;
        r[4] = rb.x; r[5] = rb.y; r[6] = rb.z; r[7] = rb.w;
        c[0] = ca.x; c[1] = ca.y; c[2] = ca.z; c[3] = ca.w;
        c[4] = cb.x; c[5] = cb.y; c[6] = cb.z; c[7] = cb.w;
        ww[0] = wa.x; ww[1] = wa.y; ww[2] = wa.z; ww[3] = wa.w;
        ww[4] = wb.x; ww[5] = wb.y; ww[6] = wb.z; ww[7] = wb.w;
        nv = 8;
    } else {
        for (int j = 0; j < 8; ++j)
            if (base + j < E) { r[nv] = row[base + j]; c[nv] = col[base + j];
                                ww[nv] = w[base + j]; ++nv; }
    }
    #pragma unroll 8
    for (int j = 0; j < 8; ++j) {
        if (j >= nv) break;
        int b = r[j] >> BSH;
        int rank = atomicAdd(&h[b], 1);
        int pos = off[(size_t)b * nT + tile] + rank;
        tmp[pos] = make_int2(((r[j] & (RPB - 1)) << 25) | c[j], __float_as_int(ww[j]));
    }
}

__global__ __launch_bounds__(256) void bsort_kernel(const int2* __restrict__ tmp,
                                                    const int* __restrict__ start,
                                                    int2* __restrict__ pairs,
                                                    int* __restrict__ rowptr,
                                                    int N, int NB, int E) {
    __shared__ int cntB[RPB];
    __shared__ int cntS[RPB];
    __shared__ int sc[RPB];
    __shared__ int2 outP[SCAP];
    int b = blockIdx.x, t = threadIdx.x;
    int s0 = start[b], s1 = start[b + 1];
    int len = s1 - s0;
    if (len > SCAP) len = SCAP;

    if (t < RPB) cntB[t] = 0;
    __syncthreads();

    int2 p[16];
    int np = 0;
    #pragma unroll
    for (int k = 0; k < 16; ++k) {
        int i = t + k * 256;
        if (i < len) { p[k] = tmp[s0 + i]; ++np; }
    }
    #pragma unroll
    for (int k = 0; k < 16; ++k) {
        if (k >= np) break;
        atomicAdd(&cntB[((unsigned)p[k].x) >> 25], 1);
    }
    __syncthreads();
    int val = (t < RPB) ? cntB[t] : 0;
    if (t < RPB) sc[t] = val;
    __syncthreads();
    #pragma unroll
    for (int o = 1; o < RPB; o <<= 1) {
        int add = (t < RPB && t >= o) ? sc[t - o] : 0;
        __syncthreads();
        if (t < RPB) sc[t] += add;
        __syncthreads();
    }
    if (t < RPB) { int ex = sc[t] - val; cntB[t] = ex; cntS[t] = ex; }
    __syncthreads();
    #pragma unroll
    for (int k = 0; k < 16; ++k) {
        if (k >= np) break;
        int rl = ((unsigned)p[k].x) >> 25;
        int lr = atomicAdd(&cntB[rl], 1);
        outP[lr] = make_int2(p[k].x & 0x1ffffff, p[k].y);
    }
    __syncthreads();
    for (int i = t; i < len; i += 256) pairs[s0 + i] = outP[i];
    int r0 = b * RPB;
    if (t < RPB && r0 + t < N) rowptr[r0 + t] = s0 + cntS[t];
    if (b == NB - 1 && t == 0) rowptr[N] = E;
}

// ---------------------------------------------------------------------------
// CSR SpMM (round-0 proven structure): one wave per row; lane groups of 16
// handle 4 edges concurrently (uint4 = 8 feats per lane, MLP-4); shfl_xor
// reduction.  256-B contiguous gathers per edge — the proven-fast granule.
// bf16 output (buf1) stays CACHED (re-read by bnstats+gemm2); fp32 output
// (final, never re-read) is NT-stored to avoid polluting L2 under gathers.
// ---------------------------------------------------------------------------
template <bool BF16OUT>
__global__ __launch_bounds__(256) void spmm_csr_kernel(const int* __restrict__ rowptr,
                                                       const int2* __restrict__ pairs,
                                                       const unsigned int* __restrict__ Hb,
                                                       const float* __restrict__ bias,
                                                       void* __restrict__ outv, int N) {
    int r = blockIdx.x * 4 + (threadIdx.x >> 6);
    if (r >= N) return;
    const int l = threadIdx.x & 63;
    const int g = l >> 4, q = l & 15;          // edge subgroup, 8-feat chunk
    const uint4* H4 = (const uint4*)Hb;        // row = 16 uint4

    float acc[8];
    #pragma unroll
    for (int j = 0; j < 8; ++j) acc[j] = 0.f;

    int i = rowptr[r], end = rowptr[r + 1];

    for (; i + 16 <= end; i += 16) {
        int2 p[4];
        uint4 gv[4];
        #pragma unroll
        for (int k = 0; k < 4; ++k) p[k] = pairs[i + 4 * k + g];
        #pragma unroll
        for (int k = 0; k < 4; ++k) gv[k] = H4[(size_t)p[k].x * 16 + q];
        #pragma unroll
        for (int k = 0; k < 4; ++k) {
            float wt = __int_as_float(p[k].y);
            unsigned int uu[4] = {gv[k].x, gv[k].y, gv[k].z, gv[k].w};
            #pragma unroll
            for (int j = 0; j < 4; ++j) {
                acc[2 * j]     = fmaf(wt, __uint_as_float(uu[j] << 16), acc[2 * j]);
                acc[2 * j + 1] = fmaf(wt, __uint_as_float(uu[j] & 0xffff0000u), acc[2 * j + 1]);
            }
        }
    }
    for (; i + 4 <= end; i += 4) {
        int2 p = pairs[i + g];
        uint4 gv = H4[(size_t)p.x * 16 + q];
        float wt = __int_as_float(p.y);
        unsigned int uu[4] = {gv.x, gv.y, gv.z, gv.w};
        #pragma unroll
        for (int j = 0; j < 4; ++j) {
            acc[2 * j]     = fmaf(wt, __uint_as_float(uu[j] << 16), acc[2 * j]);
            acc[2 * j + 1] = fmaf(wt, __uint_as_float(uu[j] & 0xffff0000u), acc[2 * j + 1]);
        }
    }
    if (i < end) {
        int e = i + g;
        int2 p = (e < end) ? pairs[e] : make_int2(0, 0);   // wt=0 for pad lanes
        uint4 gv = H4[(size_t)p.x * 16 + q];
        float wt = __int_as_float(p.y);
        unsigned int uu[4] = {gv.x, gv.y, gv.z, gv.w};
        #pragma unroll
        for (int j = 0; j < 4; ++j) {
            acc[2 * j]     = fmaf(wt, __uint_as_float(uu[j] << 16), acc[2 * j]);
            acc[2 * j + 1] = fmaf(wt, __uint_as_float(uu[j] & 0xffff0000u), acc[2 * j + 1]);
        }
    }

    // reduce the 4 edge-subgroups (lanes q, q+16, q+32, q+48)
    #pragma unroll
    for (int j = 0; j < 8; ++j) {
        acc[j] += __shfl_xor(acc[j], 16, 64);
        acc[j] += __shfl_xor(acc[j], 32, 64);
    }

    if (g == 0) {
        if (bias) {
            float4 b0 = ((const float4*)bias)[q * 2];
            float4 b1 = ((const float4*)bias)[q * 2 + 1];
            acc[0] += b0.x; acc[1] += b0.y; acc[2] += b0.z; acc[3] += b0.w;
            acc[4] += b1.x; acc[5] += b1.y; acc[6] += b1.z; acc[7] += b1.w;
        }
        if (BF16OUT) {
            uint4 pk;
            pk.x = f2bf2(acc[0], acc[1]);
            pk.y = f2bf2(acc[2], acc[3]);
            pk.z = f2bf2(acc[4], acc[5]);
            pk.w = f2bf2(acc[6], acc[7]);
            ((uint4*)outv)[(size_t)r * 16 + q] = pk;           // cached: re-read
        } else {
            f32x4 v0 = (f32x4){acc[0], acc[1], acc[2], acc[3]};
            f32x4 v1 = (f32x4){acc[4], acc[5], acc[6], acc[7]};
            f32x4* O = (f32x4*)outv;
            __builtin_nontemporal_store(v0, &O[(size_t)r * 32 + q * 2]);
            __builtin_nontemporal_store(v1, &O[(size_t)r * 32 + q * 2 + 1]);
        }
    }
}

// ---------------------------------------------------------------------------
// BN batch statistics over packed-bf16 input: per-feature sum and sumsq.
// ---------------------------------------------------------------------------
__global__ __launch_bounds__(256) void bnstats_kernel(const unsigned int* __restrict__ Hu,
                                                      float* __restrict__ sums,
                                                      int nNodes) {
    int u = threadIdx.x & 63;   // uint index: feats 2u, 2u+1
    int g = threadIdx.x >> 6;   // 0..3
    int stride = gridDim.x * 4;
    float s0 = 0.f, s1 = 0.f, q0 = 0.f, q1 = 0.f;
    for (int n = blockIdx.x * 4 + g; n < nNodes; n += stride) {
        unsigned int v = Hu[(size_t)n * FU + u];
        float a = __uint_as_float(v << 16);
        float b = __uint_as_float(v & 0xffff0000u);
        s0 += a; s1 += b;
        q0 = fmaf(a, a, q0); q1 = fmaf(b, b, q1);
    }
    __shared__ float4 red[256];
    red[threadIdx.x] = make_float4(s0, s1, q0, q1);
    __syncthreads();
    if (g == 0) {
        float4 r0 = red[u], r1 = red[64 + u], r2 = red[128 + u], r3 = red[192 + u];
        atomicAdd(&sums[2 * u],           r0.x + r1.x + r2.x + r3.x);
        atomicAdd(&sums[2 * u + 1],       r0.y + r1.y + r2.y + r3.y);
        atomicAdd(&sums[128 + 2 * u],     r0.z + r1.z + r2.z + r3.z);
        atomicAdd(&sums[128 + 2 * u + 1], r0.w + r1.w + r2.w + r3.w);
    }
}

extern "C" void kernel_launch(void* const* d_in, const int* in_sizes, int n_in,
                              void* d_out, int out_size, void* d_ws, size_t ws_size,
                              hipStream_t stream) {
    const float* x    = (const float*)d_in[0];
    const int*   erow = (const int*)d_in[1];
    const int*   ecol = (const int*)d_in[2];
    const float* ew   = (const float*)d_in[3];
    const float* W1   = (const float*)d_in[4];
    // d_in[5] = b1: unused — cancels exactly under BatchNorm mean subtraction.
    const float* W2   = (const float*)d_in[6];
    const float* b2   = (const float*)d_in[7];
    const float* gmm  = (const float*)d_in[8];
    const float* beta = (const float*)d_in[9];
    float* out = (float*)d_out;

    const int N = in_sizes[0] / F;   // 100000
    const int E = in_sizes[1];       // 1600000

    const int NB = (N + RPB - 1) / RPB;     // 782
    const int nT = (E + TILE - 1) / TILE;   // 782

    // ---- workspace carve-up ----
    unsigned int* buf1   = (unsigned int*)d_ws;                   // N*FU bf16 (h1)
    unsigned int* Hb     = buf1 + (size_t)N * FU;                 // N*FU bf16 (h0/h2)
    float*        stats  = (float*)(Hb + (size_t)N * FU);         // 256
    unsigned int* wt1    = (unsigned int*)(stats + 256);          // 8192 (W1 bf16 [f][k])
    unsigned int* wt2    = wt1 + 8192;                            // 8192 (W2 bf16 [f][k])
    int*          rowptr = (int*)(wt2 + 8192);                    // N+2
    int*          start  = rowptr + N + 2;                        // 1028
    int*          total  = start + 1028;                          // 1024
    int*          hist   = total + 1024;                          // nT*NB
    int*          off    = hist + (size_t)nT * NB;                // NB*nT
    int2*         tmp    = (int2*)(off + (size_t)NB * nT);        // E
    int2*         pairs  = tmp + E;                               // E

    const int gemmGrid = (N + 63) / 64;
    const int spmmGrid = (N + 3) / 4;

    hipMemsetAsync(stats, 0, 256 * sizeof(float), stream);

    // ---- one-time W pre-pack (bf16, transposed) ----
    wconv_kernel<<<2, 256, 0, stream>>>(W1, W2, wt1, wt2);

    // ---- build CSR: deterministic bucket sort, shared by both layers ----
    histo_kernel<<<nT, 256, 0, stream>>>(erow, hist, NB, E);
    btot_kernel<<<NB, 256, 0, stream>>>(hist, total, nT, NB);
    bstart_kernel<<<1, 1024, 0, stream>>>(total, start, NB, E);
    boff_kernel<<<NB, 1024, 0, stream>>>(hist, start, off, nT, NB);
    bplace_kernel<<<nT, 256, 0, stream>>>(erow, ecol, ew, off, tmp, nT, NB, E);
    bsort_kernel<<<NB, 256, 0, stream>>>(tmp, start, pairs, rowptr, N, NB, E);

    // Layer 1: Hb = bf16(x @ W1) ; buf1 = bf16(A @ Hb)
    gemm_kernel<false><<<gemmGrid, 256, 0, stream>>>(x, wt1, nullptr, nullptr,
                                                     nullptr, 0.f, Hb, N);
    spmm_csr_kernel<true><<<spmmGrid, 256, 0, stream>>>(rowptr, pairs, Hb,
                                                        nullptr, buf1, N);
    // BN stats (BN-fold happens inside gemm<true>)
    bnstats_kernel<<<400, 256, 0, stream>>>(buf1, stats, N);
    // Layer 2: Hb = bf16(relu(bn(buf1)) @ W2) ; out = A @ Hb + b2 (fp32)
    gemm_kernel<true><<<gemmGrid, 256, 0, stream>>>(buf1, wt2, stats, gmm, beta,
                                                    1.0f / (float)N, Hb, N);
    spmm_csr_kernel<false><<<spmmGrid, 256, 0, stream>>>(rowptr, pairs, Hb,
                                                         b2, out, N);
}

// Round 8
// 385.374 us; speedup vs baseline: 1.0985x; 1.0307x over previous
//
#include <hip/hip_runtime.h>

#define F    128
#define FQ   32    // F/4 (float4 per row)
#define FU   64    // uints per bf16 row
#define RPB  128   // rows per bucket
#define BSH  7     // log2(RPB)
#define TILE 8192  // edges per histogram tile (4 x 2048): 10.5 edges/bucket/tile
#define SCAP 4096  // max edges per bucket section (mean 2046, +45 sigma)
#define LSTR 68    // LDS row stride in dwords (136 bf16): 16-B aligned, 2-way banks

typedef __attribute__((ext_vector_type(8))) short short8;   // MFMA A/B frag (8 bf16)
typedef __attribute__((ext_vector_type(4))) float f32x4;    // MFMA C/D frag

// pack two fp32 -> two bf16 (RNE) in one uint (a = low = even feature)
__device__ __forceinline__ unsigned int f2bf2(float a, float b) {
    unsigned int ua = __float_as_uint(a);
    unsigned int ub = __float_as_uint(b);
    ua = (ua + 0x7fffu + ((ua >> 16) & 1u)) >> 16;
    ub = (ub + 0x7fffu + ((ub >> 16) & 1u)) >> 16;
    return ua | (ub << 16);
}
__device__ __forceinline__ unsigned short f2bf1(float a) {
    unsigned int ua = __float_as_uint(a);
    return (unsigned short)((ua + 0x7fffu + ((ua >> 16) & 1u)) >> 16);
}

// ---------------------------------------------------------------------------
// MFMA GEMM body: H[n][f] = sum_k In[n][k] * W[k][f] -> packed bf16 [N][128].
// W arrives PRE-PACKED bf16 [f][k].  BN=true applies relu(a*x+c) at staging
// with a,c computed from stats/gamma/beta (bnfinal folded in).
// Used standalone (gemm2) and inside the fused bplace+gemm dispatch (gemm1).
// ---------------------------------------------------------------------------
template <bool BN>
__device__ __forceinline__ void gemm_body(unsigned int* __restrict__ XtU,
                                          unsigned int* __restrict__ WtU,
                                          const void* __restrict__ Xv,
                                          const unsigned int* __restrict__ Wt,
                                          const float* __restrict__ stats,
                                          const float* __restrict__ gamma,
                                          const float* __restrict__ beta,
                                          float invN,
                                          unsigned int* __restrict__ Hb,
                                          int nNodes, int bid) {
    const int tid = threadIdx.x;
    const int bn0 = bid * 64;

    // ---- stage W (coalesced uint4 copy of pre-packed bf16) ----
    {
        int f = tid >> 1;
        int kh = (tid & 1) * 32;               // uint offset within 64-uint row
        const uint4* Wg4 = (const uint4*)Wt;   // f-row = 16 uint4
        #pragma unroll
        for (int j = 0; j < 8; ++j) {
            uint4 pk = Wg4[f * 16 + (kh >> 2) + j];
            *(uint4*)&WtU[f * LSTR + kh + j * 4] = pk;
        }
    }
    // ---- stage X tile as bf16, optional BN+ReLU ----
    {
        const int kq = tid & 31;               // constant across it-loop
        float4 a4, c4;
        if (BN) {
            float4 s  = ((const float4*)stats)[kq];
            float4 sq = ((const float4*)(stats + 128))[kq];
            float4 g4 = ((const float4*)gamma)[kq];
            float4 b4 = ((const float4*)beta)[kq];
            float m;
            m = s.x * invN; a4.x = g4.x * rsqrtf(sq.x * invN - m * m + 1e-5f); c4.x = b4.x - m * a4.x;
            m = s.y * invN; a4.y = g4.y * rsqrtf(sq.y * invN - m * m + 1e-5f); c4.y = b4.y - m * a4.y;
            m = s.z * invN; a4.z = g4.z * rsqrtf(sq.z * invN - m * m + 1e-5f); c4.z = b4.z - m * a4.z;
            m = s.w * invN; a4.w = g4.w * rsqrtf(sq.w * invN - m * m + 1e-5f); c4.w = b4.w - m * a4.w;
        }
        #pragma unroll
        for (int it = 0; it < 8; ++it) {
            int i = tid + it * 256;            // 0..2047
            int n = i >> 5;                    // node 0..63
            int node = bn0 + n;
            uint2 pk = make_uint2(0u, 0u);
            if (BN) {
                uint2 raw = make_uint2(0u, 0u);
                if (node < nNodes) raw = ((const uint2*)Xv)[(size_t)node * 32 + kq];
                float4 v;
                v.x = __uint_as_float(raw.x << 16);
                v.y = __uint_as_float(raw.x & 0xffff0000u);
                v.z = __uint_as_float(raw.y << 16);
                v.w = __uint_as_float(raw.y & 0xffff0000u);
                v.x = fmaxf(fmaf(a4.x, v.x, c4.x), 0.f);
                v.y = fmaxf(fmaf(a4.y, v.y, c4.y), 0.f);
                v.z = fmaxf(fmaf(a4.z, v.z, c4.z), 0.f);
                v.w = fmaxf(fmaf(a4.w, v.w, c4.w), 0.f);
                pk = make_uint2(f2bf2(v.x, v.y), f2bf2(v.z, v.w));
            } else {
                float4 v = make_float4(0.f, 0.f, 0.f, 0.f);
                if (node < nNodes) v = ((const float4*)Xv)[(size_t)node * FQ + kq];
                pk = make_uint2(f2bf2(v.x, v.y), f2bf2(v.z, v.w));
            }
            *(uint2*)&XtU[n * LSTR + kq * 2] = pk;
        }
    }
    __syncthreads();

    // ---- MFMA compute ----
    const int l = tid & 63;
    const int wv = tid >> 6;
    const int quad = l >> 4, lo = l & 15;
    const int fb = wv * 32;

    f32x4 acc[4][2];
    #pragma unroll
    for (int nt = 0; nt < 4; ++nt)
        #pragma unroll
        for (int ft = 0; ft < 2; ++ft) acc[nt][ft] = (f32x4){0.f, 0.f, 0.f, 0.f};

    #pragma unroll
    for (int kc = 0; kc < 4; ++kc) {
        int koff = kc * 16 + quad * 4;
        short8 a[4], b[2];
        #pragma unroll
        for (int nt = 0; nt < 4; ++nt)
            a[nt] = *(const short8*)&XtU[(nt * 16 + lo) * LSTR + koff];
        #pragma unroll
        for (int ft = 0; ft < 2; ++ft)
            b[ft] = *(const short8*)&WtU[(fb + ft * 16 + lo) * LSTR + koff];
        #pragma unroll
        for (int nt = 0; nt < 4; ++nt)
            #pragma unroll
            for (int ft = 0; ft < 2; ++ft)
                acc[nt][ft] = __builtin_amdgcn_mfma_f32_16x16x32_bf16(
                    a[nt], b[ft], acc[nt][ft], 0, 0, 0);
    }

    // ---- epilogue: bf16 store (D: col=lane&15, row=quad*4+reg) ----
    unsigned short* Hs = (unsigned short*)Hb;
    #pragma unroll
    for (int nt = 0; nt < 4; ++nt) {
        #pragma unroll
        for (int reg = 0; reg < 4; ++reg) {
            int node = bn0 + nt * 16 + quad * 4 + reg;
            if (node < nNodes) {
                #pragma unroll
                for (int ft = 0; ft < 2; ++ft)
                    Hs[(size_t)node * F + fb + ft * 16 + lo] = f2bf1(acc[nt][ft][reg]);
            }
        }
    }
}

template <bool BN>
__global__ __launch_bounds__(256) void gemm_kernel(const void* __restrict__ Xv,
                                                   const unsigned int* __restrict__ Wt,
                                                   const float* __restrict__ stats,
                                                   const float* __restrict__ gamma,
                                                   const float* __restrict__ beta,
                                                   float invN,
                                                   unsigned int* __restrict__ Hb,
                                                   int nNodes) {
    __shared__ unsigned int shm[192 * LSTR];
    gemm_body<BN>(shm, shm + 64 * LSTR, Xv, Wt, stats, gamma, beta, invN, Hb,
                  nNodes, blockIdx.x);
}

// ---------------------------------------------------------------------------
// Fused W pre-pack + edge histogram (independent; blocks 0-1 = wconv).
// ---------------------------------------------------------------------------
__global__ __launch_bounds__(256) void wchisto_kernel(const float* __restrict__ W1,
                                                      const float* __restrict__ W2,
                                                      unsigned int* __restrict__ Wt1,
                                                      unsigned int* __restrict__ Wt2,
                                                      const int* __restrict__ row,
                                                      int* __restrict__ hist,
                                                      int NB, int E) {
    __shared__ int h[1024];
    if (blockIdx.x < 2) {
        const float* W = blockIdx.x ? W2 : W1;
        unsigned int* Wt = blockIdx.x ? Wt2 : Wt1;
        int f = threadIdx.x & 127;
        int kh = (threadIdx.x >> 7) * 64;
        #pragma unroll
        for (int k8 = 0; k8 < 8; ++k8) {
            int k0 = kh + k8 * 8;
            float v[8];
            #pragma unroll
            for (int i = 0; i < 8; ++i) v[i] = W[(size_t)(k0 + i) * F + f];
            uint4 pk;
            pk.x = f2bf2(v[0], v[1]);
            pk.y = f2bf2(v[2], v[3]);
            pk.z = f2bf2(v[4], v[5]);
            pk.w = f2bf2(v[6], v[7]);
            *(uint4*)&Wt[f * 64 + k0 / 2] = pk;
        }
        return;
    }
    const int tile = blockIdx.x - 2;
    const int t = threadIdx.x;
    for (int i = t; i < NB; i += 256) h[i] = 0;
    __syncthreads();
    #pragma unroll 1
    for (int c = 0; c < TILE / 2048; ++c) {
        int base = tile * TILE + c * 2048 + t * 8;
        if (base + 7 < E) {
            int4 a = ((const int4*)row)[(base >> 2) + 0];
            int4 b = ((const int4*)row)[(base >> 2) + 1];
            atomicAdd(&h[a.x >> BSH], 1); atomicAdd(&h[a.y >> BSH], 1);
            atomicAdd(&h[a.z >> BSH], 1); atomicAdd(&h[a.w >> BSH], 1);
            atomicAdd(&h[b.x >> BSH], 1); atomicAdd(&h[b.y >> BSH], 1);
            atomicAdd(&h[b.z >> BSH], 1); atomicAdd(&h[b.w >> BSH], 1);
        } else {
            for (int j = 0; j < 8; ++j)
                if (base + j < E) atomicAdd(&h[row[base + j] >> BSH], 1);
        }
    }
    __syncthreads();
    for (int i = t; i < NB; i += 256) hist[(size_t)tile * NB + i] = h[i];
}

__global__ __launch_bounds__(256) void btot_kernel(const int* __restrict__ hist,
                                                   int* __restrict__ total,
                                                   int nT, int NB) {
    int b = blockIdx.x;
    int s = 0;
    for (int t = threadIdx.x; t < nT; t += 256) s += hist[(size_t)t * NB + b];
    __shared__ int red[256];
    red[threadIdx.x] = s;
    __syncthreads();
    for (int o = 128; o > 0; o >>= 1) {
        if (threadIdx.x < o) red[threadIdx.x] += red[threadIdx.x + o];
        __syncthreads();
    }
    if (threadIdx.x == 0) total[b] = red[0];
}

// ---------------------------------------------------------------------------
// Merged bstart+boff: each block redundantly scans the (<=1024) bucket totals
// in LDS to get its own start[b] (kills the single-block bstart dispatch),
// then scans its bucket's per-tile histogram to produce placement offsets.
// ---------------------------------------------------------------------------
__global__ __launch_bounds__(1024) void boffs_kernel(const int* __restrict__ hist,
                                                     const int* __restrict__ total,
                                                     int* __restrict__ start,
                                                     int* __restrict__ off,
                                                     int nT, int NB, int E) {
    __shared__ int sh[1024];
    const int b = blockIdx.x, t = threadIdx.x;
    int tv = (t < NB) ? total[t] : 0;
    sh[t] = tv;
    __syncthreads();
    #pragma unroll
    for (int o = 1; o < 1024; o <<= 1) {
        int add = (t >= o) ? sh[t - o] : 0;
        __syncthreads();
        sh[t] += add;
        __syncthreads();
    }
    const int s0 = (b > 0) ? sh[b - 1] : 0;    // exclusive prefix at bucket b
    if (t == 0) {
        start[b] = s0;
        if (b == NB - 1) start[NB] = E;
    }
    __syncthreads();
    int v = (t < nT) ? hist[(size_t)t * NB + b] : 0;
    sh[t] = v;
    __syncthreads();
    #pragma unroll
    for (int o = 1; o < 1024; o <<= 1) {
        int add = (t >= o) ? sh[t - o] : 0;
        __syncthreads();
        sh[t] += add;
        __syncthreads();
    }
    if (t < nT) off[(size_t)b * nT + t] = s0 + sh[t] - v;
}

// ---------------------------------------------------------------------------
// bplace body: scatter edges to bucket sections (tile-ordered).  TILE=8192
// gives ~10.5 edges per (bucket,tile) = 84-B write clusters (was 2.6 / 21 B
// at TILE=2048 -> isolated-line RMW traffic, the old bplace cost).
// ---------------------------------------------------------------------------
__device__ __forceinline__ void bplace_body(int* __restrict__ h,
                                            const int* __restrict__ row,
                                            const int* __restrict__ col,
                                            const float* __restrict__ w,
                                            const int* __restrict__ off,
                                            int2* __restrict__ tmp,
                                            int nT, int NB, int E, int tile) {
    const int t = threadIdx.x;
    for (int i = t; i < NB; i += 256) h[i] = 0;
    __syncthreads();
    #pragma unroll 1
    for (int c = 0; c < TILE / 2048; ++c) {
        int base = tile * TILE + c * 2048 + t * 8;
        int r[8], cc[8];
        float ww[8];
        int nv = 0;
        if (base + 7 < E) {
            int4 ra = ((const int4*)row)[(base >> 2) + 0];
            int4 rb = ((const int4*)row)[(base >> 2) + 1];
            int4 ca = ((const int4*)col)[(base >> 2) + 0];
            int4 cb = ((const int4*)col)[(base >> 2) + 1];
            float4 wa = ((const float4*)w)[(base >> 2) + 0];
            float4 wb = ((const float4*)w)[(base >> 2) + 1];
            r[0] = ra.x; r[1] = ra.y; r[2] = ra.z; r[3] = ra.w;
            r[4] = rb.x; r[5] = rb.y; r[6] = rb.z; r[7] = rb.w;
            cc[0] = ca.x; cc[1] = ca.y; cc[2] = ca.z; cc[3] = ca.w;
            cc[4] = cb.x; cc[5] = cb.y; cc[6] = cb.z; cc[7] = cb.w;
            ww[0] = wa.x; ww[1] = wa.y; ww[2] = wa.z; ww[3] = wa.w;
            ww[4] = wb.x; ww[5] = wb.y; ww[6] = wb.z; ww[7] = wb.w;
            nv = 8;
        } else {
            for (int j = 0; j < 8; ++j)
                if (base + j < E) { r[nv] = row[base + j]; cc[nv] = col[base + j];
                                    ww[nv] = w[base + j]; ++nv; }
        }
        #pragma unroll 8
        for (int j = 0; j < 8; ++j) {
            if (j >= nv) break;
            int b = r[j] >> BSH;
            int rank = atomicAdd(&h[b], 1);
            int pos = off[(size_t)b * nT + tile] + rank;
            tmp[pos] = make_int2(((r[j] & (RPB - 1)) << 25) | cc[j], __float_as_int(ww[j]));
        }
    }
}

// ---------------------------------------------------------------------------
// Fused bplace + gemm1 (independent work, one dispatch): blocks [0,nT) do
// edge placement; blocks [nT, nT+gemmGrid) run layer-1 GEMM.  Shared LDS
// buffer aliased by both branches (52 KB -> gemm keeps 3 blocks/CU).
// ---------------------------------------------------------------------------
__global__ __launch_bounds__(256) void bpgemm_kernel(const int* __restrict__ row,
                                                     const int* __restrict__ col,
                                                     const float* __restrict__ w,
                                                     const int* __restrict__ off,
                                                     int2* __restrict__ tmp,
                                                     const float* __restrict__ x,
                                                     const unsigned int* __restrict__ wt1,
                                                     unsigned int* __restrict__ Hb,
                                                     int nT, int NB, int E, int nNodes) {
    __shared__ unsigned int shm[192 * LSTR];
    if (blockIdx.x < (unsigned)nT) {
        bplace_body((int*)shm, row, col, w, off, tmp, nT, NB, E, blockIdx.x);
    } else {
        gemm_body<false>(shm, shm + 64 * LSTR, x, wt1, nullptr, nullptr, nullptr,
                         0.f, Hb, nNodes, blockIdx.x - nT);
    }
}

__global__ __launch_bounds__(256) void bsort_kernel(const int2* __restrict__ tmp,
                                                    const int* __restrict__ start,
                                                    int2* __restrict__ pairs,
                                                    int* __restrict__ rowptr,
                                                    int N, int NB, int E) {
    __shared__ int cntB[RPB];
    __shared__ int cntS[RPB];
    __shared__ int sc[RPB];
    __shared__ int2 outP[SCAP];
    int b = blockIdx.x, t = threadIdx.x;
    int s0 = start[b], s1 = start[b + 1];
    int len = s1 - s0;
    if (len > SCAP) len = SCAP;

    if (t < RPB) cntB[t] = 0;
    __syncthreads();

    int2 p[16];
    int np = 0;
    #pragma unroll
    for (int k = 0; k < 16; ++k) {
        int i = t + k * 256;
        if (i < len) { p[k] = tmp[s0 + i]; ++np; }
    }
    #pragma unroll
    for (int k = 0; k < 16; ++k) {
        if (k >= np) break;
        atomicAdd(&cntB[((unsigned)p[k].x) >> 25], 1);
    }
    __syncthreads();
    int val = (t < RPB) ? cntB[t] : 0;
    if (t < RPB) sc[t] = val;
    __syncthreads();
    #pragma unroll
    for (int o = 1; o < RPB; o <<= 1) {
        int add = (t < RPB && t >= o) ? sc[t - o] : 0;
        __syncthreads();
        if (t < RPB) sc[t] += add;
        __syncthreads();
    }
    if (t < RPB) { int ex = sc[t] - val; cntB[t] = ex; cntS[t] = ex; }
    __syncthreads();
    #pragma unroll
    for (int k = 0; k < 16; ++k) {
        if (k >= np) break;
        int rl = ((unsigned)p[k].x) >> 25;
        int lr = atomicAdd(&cntB[rl], 1);
        outP[lr] = make_int2(p[k].x & 0x1ffffff, p[k].y);
    }
    __syncthreads();
    for (int i = t; i < len; i += 256) pairs[s0 + i] = outP[i];
    int r0 = b * RPB;
    if (t < RPB && r0 + t < N) rowptr[r0 + t] = s0 + cntS[t];
    if (b == NB - 1 && t == 0) rowptr[N] = E;
}

// ---------------------------------------------------------------------------
// CSR SpMM (round-0 proven structure): one wave per row; 4 edge-subgroups x
// 16 lanes (uint4 = 8 feats per lane, MLP-4); shfl_xor reduction.  bf16 out
// cached (re-read); fp32 out NT-stored (never re-read).
// ---------------------------------------------------------------------------
template <bool BF16OUT>
__global__ __launch_bounds__(256) void spmm_csr_kernel(const int* __restrict__ rowptr,
                                                       const int2* __restrict__ pairs,
                                                       const unsigned int* __restrict__ Hb,
                                                       const float* __restrict__ bias,
                                                       void* __restrict__ outv, int N) {
    int r = blockIdx.x * 4 + (threadIdx.x >> 6);
    if (r >= N) return;
    const int l = threadIdx.x & 63;
    const int g = l >> 4, q = l & 15;          // edge subgroup, 8-feat chunk
    const uint4* H4 = (const uint4*)Hb;        // row = 16 uint4

    float acc[8];
    #pragma unroll
    for (int j = 0; j < 8; ++j) acc[j] = 0.f;

    int i = rowptr[r], end = rowptr[r + 1];

    for (; i + 16 <= end; i += 16) {
        int2 p[4];
        uint4 gv[4];
        #pragma unroll
        for (int k = 0; k < 4; ++k) p[k] = pairs[i + 4 * k + g];
        #pragma unroll
        for (int k = 0; k < 4; ++k) gv[k] = H4[(size_t)p[k].x * 16 + q];
        #pragma unroll
        for (int k = 0; k < 4; ++k) {
            float wt = __int_as_float(p[k].y);
            unsigned int uu[4] = {gv[k].x, gv[k].y, gv[k].z, gv[k].w};
            #pragma unroll
            for (int j = 0; j < 4; ++j) {
                acc[2 * j]     = fmaf(wt, __uint_as_float(uu[j] << 16), acc[2 * j]);
                acc[2 * j + 1] = fmaf(wt, __uint_as_float(uu[j] & 0xffff0000u), acc[2 * j + 1]);
            }
        }
    }
    for (; i + 4 <= end; i += 4) {
        int2 p = pairs[i + g];
        uint4 gv = H4[(size_t)p.x * 16 + q];
        float wt = __int_as_float(p.y);
        unsigned int uu[4] = {gv.x, gv.y, gv.z, gv.w};
        #pragma unroll
        for (int j = 0; j < 4; ++j) {
            acc[2 * j]     = fmaf(wt, __uint_as_float(uu[j] << 16), acc[2 * j]);
            acc[2 * j + 1] = fmaf(wt, __uint_as_float(uu[j] & 0xffff0000u), acc[2 * j + 1]);
        }
    }
    if (i < end) {
        int e = i + g;
        int2 p = (e < end) ? pairs[e] : make_int2(0, 0);   // wt=0 for pad lanes
        uint4 gv = H4[(size_t)p.x * 16 + q];
        float wt = __int_as_float(p.y);
        unsigned int uu[4] = {gv.x, gv.y, gv.z, gv.w};
        #pragma unroll
        for (int j = 0; j < 4; ++j) {
            acc[2 * j]     = fmaf(wt, __uint_as_float(uu[j] << 16), acc[2 * j]);
            acc[2 * j + 1] = fmaf(wt, __uint_as_float(uu[j] & 0xffff0000u), acc[2 * j + 1]);
        }
    }

    // reduce the 4 edge-subgroups (lanes q, q+16, q+32, q+48)
    #pragma unroll
    for (int j = 0; j < 8; ++j) {
        acc[j] += __shfl_xor(acc[j], 16, 64);
        acc[j] += __shfl_xor(acc[j], 32, 64);
    }

    if (g == 0) {
        if (bias) {
            float4 b0 = ((const float4*)bias)[q * 2];
            float4 b1 = ((const float4*)bias)[q * 2 + 1];
            acc[0] += b0.x; acc[1] += b0.y; acc[2] += b0.z; acc[3] += b0.w;
            acc[4] += b1.x; acc[5] += b1.y; acc[6] += b1.z; acc[7] += b1.w;
        }
        if (BF16OUT) {
            uint4 pk;
            pk.x = f2bf2(acc[0], acc[1]);
            pk.y = f2bf2(acc[2], acc[3]);
            pk.z = f2bf2(acc[4], acc[5]);
            pk.w = f2bf2(acc[6], acc[7]);
            ((uint4*)outv)[(size_t)r * 16 + q] = pk;           // cached: re-read
        } else {
            f32x4 v0 = (f32x4){acc[0], acc[1], acc[2], acc[3]};
            f32x4 v1 = (f32x4){acc[4], acc[5], acc[6], acc[7]};
            f32x4* O = (f32x4*)outv;
            __builtin_nontemporal_store(v0, &O[(size_t)r * 32 + q * 2]);
            __builtin_nontemporal_store(v1, &O[(size_t)r * 32 + q * 2 + 1]);
        }
    }
}

// ---------------------------------------------------------------------------
// BN batch statistics over packed-bf16 input: per-feature sum and sumsq.
// ---------------------------------------------------------------------------
__global__ __launch_bounds__(256) void bnstats_kernel(const unsigned int* __restrict__ Hu,
                                                      float* __restrict__ sums,
                                                      int nNodes) {
    int u = threadIdx.x & 63;   // uint index: feats 2u, 2u+1
    int g = threadIdx.x >> 6;   // 0..3
    int stride = gridDim.x * 4;
    float s0 = 0.f, s1 = 0.f, q0 = 0.f, q1 = 0.f;
    for (int n = blockIdx.x * 4 + g; n < nNodes; n += stride) {
        unsigned int v = Hu[(size_t)n * FU + u];
        float a = __uint_as_float(v << 16);
        float b = __uint_as_float(v & 0xffff0000u);
        s0 += a; s1 += b;
        q0 = fmaf(a, a, q0); q1 = fmaf(b, b, q1);
    }
    __shared__ float4 red[256];
    red[threadIdx.x] = make_float4(s0, s1, q0, q1);
    __syncthreads();
    if (g == 0) {
        float4 r0 = red[u], r1 = red[64 + u], r2 = red[128 + u], r3 = red[192 + u];
        atomicAdd(&sums[2 * u],           r0.x + r1.x + r2.x + r3.x);
        atomicAdd(&sums[2 * u + 1],       r0.y + r1.y + r2.y + r3.y);
        atomicAdd(&sums[128 + 2 * u],     r0.z + r1.z + r2.z + r3.z);
        atomicAdd(&sums[128 + 2 * u + 1], r0.w + r1.w + r2.w + r3.w);
    }
}

extern "C" void kernel_launch(void* const* d_in, const int* in_sizes, int n_in,
                              void* d_out, int out_size, void* d_ws, size_t ws_size,
                              hipStream_t stream) {
    const float* x    = (const float*)d_in[0];
    const int*   erow = (const int*)d_in[1];
    const int*   ecol = (const int*)d_in[2];
    const float* ew   = (const float*)d_in[3];
    const float* W1   = (const float*)d_in[4];
    // d_in[5] = b1: unused — cancels exactly under BatchNorm mean subtraction.
    const float* W2   = (const float*)d_in[6];
    const float* b2   = (const float*)d_in[7];
    const float* gmm  = (const float*)d_in[8];
    const float* beta = (const float*)d_in[9];
    float* out = (float*)d_out;

    const int N = in_sizes[0] / F;   // 100000
    const int E = in_sizes[1];       // 1600000

    const int NB = (N + RPB - 1) / RPB;     // 782
    const int nT = (E + TILE - 1) / TILE;   // 196

    // ---- workspace carve-up ----
    unsigned int* buf1   = (unsigned int*)d_ws;                   // N*FU bf16 (h1)
    unsigned int* Hb     = buf1 + (size_t)N * FU;                 // N*FU bf16 (h0/h2)
    float*        stats  = (float*)(Hb + (size_t)N * FU);         // 256
    unsigned int* wt1    = (unsigned int*)(stats + 256);          // 8192 (W1 bf16 [f][k])
    unsigned int* wt2    = wt1 + 8192;                            // 8192 (W2 bf16 [f][k])
    int*          rowptr = (int*)(wt2 + 8192);                    // N+2
    int*          start  = rowptr + N + 2;                        // 1028
    int*          total  = start + 1028;                          // 1024
    int*          hist   = total + 1024;                          // nT*NB
    int*          off    = hist + (size_t)nT * NB;                // NB*nT
    int2*         tmp    = (int2*)(off + (size_t)NB * nT);        // E
    int2*         pairs  = tmp + E;                               // E

    const int gemmGrid = (N + 63) / 64;
    const int spmmGrid = (N + 3) / 4;

    hipMemsetAsync(stats, 0, 256 * sizeof(float), stream);

    // ---- fused W pre-pack + histogram ----
    wchisto_kernel<<<nT + 2, 256, 0, stream>>>(W1, W2, wt1, wt2, erow, hist, NB, E);
    btot_kernel<<<NB, 256, 0, stream>>>(hist, total, nT, NB);
    boffs_kernel<<<NB, 1024, 0, stream>>>(hist, total, start, off, nT, NB, E);
    // ---- fused edge placement + layer-1 GEMM (independent) ----
    bpgemm_kernel<<<nT + gemmGrid, 256, 0, stream>>>(erow, ecol, ew, off, tmp,
                                                     x, wt1, Hb, nT, NB, E, N);
    bsort_kernel<<<NB, 256, 0, stream>>>(tmp, start, pairs, rowptr, N, NB, E);

    // Layer 1 aggregate: buf1 = bf16(A @ Hb)
    spmm_csr_kernel<true><<<spmmGrid, 256, 0, stream>>>(rowptr, pairs, Hb,
                                                        nullptr, buf1, N);
    // BN stats (BN-fold happens inside gemm<true>)
    bnstats_kernel<<<400, 256, 0, stream>>>(buf1, stats, N);
    // Layer 2: Hb = bf16(relu(bn(buf1)) @ W2) ; out = A @ Hb + b2 (fp32)
    gemm_kernel<true><<<gemmGrid, 256, 0, stream>>>(buf1, wt2, stats, gmm, beta,
                                                    1.0f / (float)N, Hb, N);
    spmm_csr_kernel<false><<<spmmGrid, 256, 0, stream>>>(rowptr, pairs, Hb,
                                                         b2, out, N);
}

// Round 9
// 380.079 us; speedup vs baseline: 1.1138x; 1.0139x over previous
//
#include <hip/hip_runtime.h>

#define F    128
#define FQ   32    // F/4 (float4 per row)
#define FU   64    // uints per bf16 row
#define RPB  128   // rows per bucket
#define BSH  7     // log2(RPB)
#define TILE 8192  // edges per histogram tile (4 x 2048): 10.5 edges/bucket/tile
#define SCAP 4096  // max edges per bucket section (mean 2046, +45 sigma)
#define LSTR 68    // LDS row stride in dwords (136 bf16): 16-B aligned, 2-way banks

typedef __attribute__((ext_vector_type(8))) short short8;   // MFMA A/B frag (8 bf16)
typedef __attribute__((ext_vector_type(4))) float f32x4;    // MFMA C/D frag

// pack two fp32 -> two bf16 (RNE) in one uint (a = low = even feature)
__device__ __forceinline__ unsigned int f2bf2(float a, float b) {
    unsigned int ua = __float_as_uint(a);
    unsigned int ub = __float_as_uint(b);
    ua = (ua + 0x7fffu + ((ua >> 16) & 1u)) >> 16;
    ub = (ub + 0x7fffu + ((ub >> 16) & 1u)) >> 16;
    return ua | (ub << 16);
}
__device__ __forceinline__ unsigned short f2bf1(float a) {
    unsigned int ua = __float_as_uint(a);
    return (unsigned short)((ua + 0x7fffu + ((ua >> 16) & 1u)) >> 16);
}

// ---------------------------------------------------------------------------
// MFMA GEMM body: H[n][f] = sum_k In[n][k] * W[k][f] -> packed bf16 [N][128].
// W arrives PRE-PACKED bf16 [f][k] and is L2-hot (32 KB, shared by all
// blocks): B-fragments load DIRECTLY global->VGPR (8 frags = 32 VGPR/lane,
// issued before X staging so L2 latency hides under it).  No W LDS stage:
// LDS 52->17.4 KB, occupancy 3->~5 blocks/CU (R8's bpgemm was latency-bound
// at 24% occupancy).  BN=true applies relu(a*x+c) at staging (bnfinal
// folded).  Used standalone (gemm2) and fused with bplace (gemm1).
// ---------------------------------------------------------------------------
template <bool BN>
__device__ __forceinline__ void gemm_body(unsigned int* __restrict__ XtU,
                                          const void* __restrict__ Xv,
                                          const unsigned int* __restrict__ Wt,
                                          const float* __restrict__ stats,
                                          const float* __restrict__ gamma,
                                          const float* __restrict__ beta,
                                          float invN,
                                          unsigned int* __restrict__ Hb,
                                          int nNodes, int bid) {
    const int tid = threadIdx.x;
    const int bn0 = bid * 64;
    const int l = tid & 63;
    const int wv = tid >> 6;
    const int quad = l >> 4, lo = l & 15;
    const int fb = wv * 32;

    // ---- B-fragments: direct global->reg (L2-hit), no LDS ----
    short8 bfrag[4][2];
    #pragma unroll
    for (int kc = 0; kc < 4; ++kc)
        #pragma unroll
        for (int ft = 0; ft < 2; ++ft)
            bfrag[kc][ft] = *(const short8*)&Wt[(size_t)(fb + ft * 16 + lo) * 64
                                                + kc * 16 + quad * 4];

    // ---- stage X tile as bf16, optional BN+ReLU ----
    {
        const int kq = tid & 31;               // constant across it-loop
        float4 a4, c4;
        if (BN) {
            float4 s  = ((const float4*)stats)[kq];
            float4 sq = ((const float4*)(stats + 128))[kq];
            float4 g4 = ((const float4*)gamma)[kq];
            float4 b4 = ((const float4*)beta)[kq];
            float m;
            m = s.x * invN; a4.x = g4.x * rsqrtf(sq.x * invN - m * m + 1e-5f); c4.x = b4.x - m * a4.x;
            m = s.y * invN; a4.y = g4.y * rsqrtf(sq.y * invN - m * m + 1e-5f); c4.y = b4.y - m * a4.y;
            m = s.z * invN; a4.z = g4.z * rsqrtf(sq.z * invN - m * m + 1e-5f); c4.z = b4.z - m * a4.z;
            m = s.w * invN; a4.w = g4.w * rsqrtf(sq.w * invN - m * m + 1e-5f); c4.w = b4.w - m * a4.w;
        }
        #pragma unroll
        for (int it = 0; it < 8; ++it) {
            int i = tid + it * 256;            // 0..2047
            int n = i >> 5;                    // node 0..63
            int node = bn0 + n;
            uint2 pk = make_uint2(0u, 0u);
            if (BN) {
                uint2 raw = make_uint2(0u, 0u);
                if (node < nNodes) raw = ((const uint2*)Xv)[(size_t)node * 32 + kq];
                float4 v;
                v.x = __uint_as_float(raw.x << 16);
                v.y = __uint_as_float(raw.x & 0xffff0000u);
                v.z = __uint_as_float(raw.y << 16);
                v.w = __uint_as_float(raw.y & 0xffff0000u);
                v.x = fmaxf(fmaf(a4.x, v.x, c4.x), 0.f);
                v.y = fmaxf(fmaf(a4.y, v.y, c4.y), 0.f);
                v.z = fmaxf(fmaf(a4.z, v.z, c4.z), 0.f);
                v.w = fmaxf(fmaf(a4.w, v.w, c4.w), 0.f);
                pk = make_uint2(f2bf2(v.x, v.y), f2bf2(v.z, v.w));
            } else {
                float4 v = make_float4(0.f, 0.f, 0.f, 0.f);
                if (node < nNodes) v = ((const float4*)Xv)[(size_t)node * FQ + kq];
                pk = make_uint2(f2bf2(v.x, v.y), f2bf2(v.z, v.w));
            }
            *(uint2*)&XtU[n * LSTR + kq * 2] = pk;
        }
    }
    __syncthreads();

    // ---- MFMA compute ----
    f32x4 acc[4][2];
    #pragma unroll
    for (int nt = 0; nt < 4; ++nt)
        #pragma unroll
        for (int ft = 0; ft < 2; ++ft) acc[nt][ft] = (f32x4){0.f, 0.f, 0.f, 0.f};

    #pragma unroll
    for (int kc = 0; kc < 4; ++kc) {
        int koff = kc * 16 + quad * 4;
        short8 a[4];
        #pragma unroll
        for (int nt = 0; nt < 4; ++nt)
            a[nt] = *(const short8*)&XtU[(nt * 16 + lo) * LSTR + koff];
        #pragma unroll
        for (int nt = 0; nt < 4; ++nt)
            #pragma unroll
            for (int ft = 0; ft < 2; ++ft)
                acc[nt][ft] = __builtin_amdgcn_mfma_f32_16x16x32_bf16(
                    a[nt], bfrag[kc][ft], acc[nt][ft], 0, 0, 0);
    }

    // ---- epilogue: bf16 store (D: col=lane&15, row=quad*4+reg) ----
    unsigned short* Hs = (unsigned short*)Hb;
    #pragma unroll
    for (int nt = 0; nt < 4; ++nt) {
        #pragma unroll
        for (int reg = 0; reg < 4; ++reg) {
            int node = bn0 + nt * 16 + quad * 4 + reg;
            if (node < nNodes) {
                #pragma unroll
                for (int ft = 0; ft < 2; ++ft)
                    Hs[(size_t)node * F + fb + ft * 16 + lo] = f2bf1(acc[nt][ft][reg]);
            }
        }
    }
}

template <bool BN>
__global__ __launch_bounds__(256) void gemm_kernel(const void* __restrict__ Xv,
                                                   const unsigned int* __restrict__ Wt,
                                                   const float* __restrict__ stats,
                                                   const float* __restrict__ gamma,
                                                   const float* __restrict__ beta,
                                                   float invN,
                                                   unsigned int* __restrict__ Hb,
                                                   int nNodes) {
    __shared__ unsigned int shm[64 * LSTR];
    gemm_body<BN>(shm, Xv, Wt, stats, gamma, beta, invN, Hb, nNodes, blockIdx.x);
}

// ---------------------------------------------------------------------------
// Fused W pre-pack + edge histogram (independent; blocks 0-1 = wconv).
// ---------------------------------------------------------------------------
__global__ __launch_bounds__(256) void wchisto_kernel(const float* __restrict__ W1,
                                                      const float* __restrict__ W2,
                                                      unsigned int* __restrict__ Wt1,
                                                      unsigned int* __restrict__ Wt2,
                                                      const int* __restrict__ row,
                                                      int* __restrict__ hist,
                                                      int NB, int E) {
    __shared__ int h[1024];
    if (blockIdx.x < 2) {
        const float* W = blockIdx.x ? W2 : W1;
        unsigned int* Wt = blockIdx.x ? Wt2 : Wt1;
        int f = threadIdx.x & 127;
        int kh = (threadIdx.x >> 7) * 64;
        #pragma unroll
        for (int k8 = 0; k8 < 8; ++k8) {
            int k0 = kh + k8 * 8;
            float v[8];
            #pragma unroll
            for (int i = 0; i < 8; ++i) v[i] = W[(size_t)(k0 + i) * F + f];
            uint4 pk;
            pk.x = f2bf2(v[0], v[1]);
            pk.y = f2bf2(v[2], v[3]);
            pk.z = f2bf2(v[4], v[5]);
            pk.w = f2bf2(v[6], v[7]);
            *(uint4*)&Wt[f * 64 + k0 / 2] = pk;
        }
        return;
    }
    const int tile = blockIdx.x - 2;
    const int t = threadIdx.x;
    for (int i = t; i < NB; i += 256) h[i] = 0;
    __syncthreads();
    #pragma unroll 1
    for (int c = 0; c < TILE / 2048; ++c) {
        int base = tile * TILE + c * 2048 + t * 8;
        if (base + 7 < E) {
            int4 a = ((const int4*)row)[(base >> 2) + 0];
            int4 b = ((const int4*)row)[(base >> 2) + 1];
            atomicAdd(&h[a.x >> BSH], 1); atomicAdd(&h[a.y >> BSH], 1);
            atomicAdd(&h[a.z >> BSH], 1); atomicAdd(&h[a.w >> BSH], 1);
            atomicAdd(&h[b.x >> BSH], 1); atomicAdd(&h[b.y >> BSH], 1);
            atomicAdd(&h[b.z >> BSH], 1); atomicAdd(&h[b.w >> BSH], 1);
        } else {
            for (int j = 0; j < 8; ++j)
                if (base + j < E) atomicAdd(&h[row[base + j] >> BSH], 1);
        }
    }
    __syncthreads();
    for (int i = t; i < NB; i += 256) hist[(size_t)tile * NB + i] = h[i];
}

__global__ __launch_bounds__(256) void btot_kernel(const int* __restrict__ hist,
                                                   int* __restrict__ total,
                                                   int nT, int NB) {
    int b = blockIdx.x;
    int s = 0;
    for (int t = threadIdx.x; t < nT; t += 256) s += hist[(size_t)t * NB + b];
    __shared__ int red[256];
    red[threadIdx.x] = s;
    __syncthreads();
    for (int o = 128; o > 0; o >>= 1) {
        if (threadIdx.x < o) red[threadIdx.x] += red[threadIdx.x + o];
        __syncthreads();
    }
    if (threadIdx.x == 0) total[b] = red[0];
}

// ---------------------------------------------------------------------------
// Merged bstart+boff: each block redundantly scans the (<=1024) bucket totals
// in LDS to get its own start[b], then scans its bucket's per-tile histogram
// to produce placement offsets.
// ---------------------------------------------------------------------------
__global__ __launch_bounds__(1024) void boffs_kernel(const int* __restrict__ hist,
                                                     const int* __restrict__ total,
                                                     int* __restrict__ start,
                                                     int* __restrict__ off,
                                                     int nT, int NB, int E) {
    __shared__ int sh[1024];
    const int b = blockIdx.x, t = threadIdx.x;
    int tv = (t < NB) ? total[t] : 0;
    sh[t] = tv;
    __syncthreads();
    #pragma unroll
    for (int o = 1; o < 1024; o <<= 1) {
        int add = (t >= o) ? sh[t - o] : 0;
        __syncthreads();
        sh[t] += add;
        __syncthreads();
    }
    const int s0 = (b > 0) ? sh[b - 1] : 0;    // exclusive prefix at bucket b
    if (t == 0) {
        start[b] = s0;
        if (b == NB - 1) start[NB] = E;
    }
    __syncthreads();
    int v = (t < nT) ? hist[(size_t)t * NB + b] : 0;
    sh[t] = v;
    __syncthreads();
    #pragma unroll
    for (int o = 1; o < 1024; o <<= 1) {
        int add = (t >= o) ? sh[t - o] : 0;
        __syncthreads();
        sh[t] += add;
        __syncthreads();
    }
    if (t < nT) off[(size_t)b * nT + t] = s0 + sh[t] - v;
}

// ---------------------------------------------------------------------------
// bplace body: scatter edges to bucket sections (tile-ordered).  TILE=8192
// gives ~10.5 edges per (bucket,tile) = 84-B write clusters.
// ---------------------------------------------------------------------------
__device__ __forceinline__ void bplace_body(int* __restrict__ h,
                                            const int* __restrict__ row,
                                            const int* __restrict__ col,
                                            const float* __restrict__ w,
                                            const int* __restrict__ off,
                                            int2* __restrict__ tmp,
                                            int nT, int NB, int E, int tile) {
    const int t = threadIdx.x;
    for (int i = t; i < NB; i += 256) h[i] = 0;
    __syncthreads();
    #pragma unroll 1
    for (int c = 0; c < TILE / 2048; ++c) {
        int base = tile * TILE + c * 2048 + t * 8;
        int r[8], cc[8];
        float ww[8];
        int nv = 0;
        if (base + 7 < E) {
            int4 ra = ((const int4*)row)[(base >> 2) + 0];
            int4 rb = ((const int4*)row)[(base >> 2) + 1];
            int4 ca = ((const int4*)col)[(base >> 2) + 0];
            int4 cb = ((const int4*)col)[(base >> 2) + 1];
            float4 wa = ((const float4*)w)[(base >> 2) + 0];
            float4 wb = ((const float4*)w)[(base >> 2) + 1];
            r[0] = ra.x; r[1] = ra.y; r[2] = ra.z; r[3] = ra.w;
            r[4] = rb.x; r[5] = rb.y; r[6] = rb.z; r[7] = rb.w;
            cc[0] = ca.x; cc[1] = ca.y; cc[2] = ca.z; cc[3] = ca.w;
            cc[4] = cb.x; cc[5] = cb.y; cc[6] = cb.z; cc[7] = cb.w;
            ww[0] = wa.x; ww[1] = wa.y; ww[2] = wa.z; ww[3] = wa.w;
            ww[4] = wb.x; ww[5] = wb.y; ww[6] = wb.z; ww[7] = wb.w;
            nv = 8;
        } else {
            for (int j = 0; j < 8; ++j)
                if (base + j < E) { r[nv] = row[base + j]; cc[nv] = col[base + j];
                                    ww[nv] = w[base + j]; ++nv; }
        }
        #pragma unroll 8
        for (int j = 0; j < 8; ++j) {
            if (j >= nv) break;
            int b = r[j] >> BSH;
            int rank = atomicAdd(&h[b], 1);
            int pos = off[(size_t)b * nT + tile] + rank;
            tmp[pos] = make_int2(((r[j] & (RPB - 1)) << 25) | cc[j], __float_as_int(ww[j]));
        }
    }
}

// ---------------------------------------------------------------------------
// Fused bplace + gemm1 (independent work, one dispatch): blocks [0,nT) do
// edge placement; blocks [nT, nT+gemmGrid) run layer-1 GEMM.  Shared LDS
// buffer aliased by both branches (17.4 KB).
// ---------------------------------------------------------------------------
__global__ __launch_bounds__(256) void bpgemm_kernel(const int* __restrict__ row,
                                                     const int* __restrict__ col,
                                                     const float* __restrict__ w,
                                                     const int* __restrict__ off,
                                                     int2* __restrict__ tmp,
                                                     const float* __restrict__ x,
                                                     const unsigned int* __restrict__ wt1,
                                                     unsigned int* __restrict__ Hb,
                                                     int nT, int NB, int E, int nNodes) {
    __shared__ unsigned int shm[64 * LSTR];
    if (blockIdx.x < (unsigned)nT) {
        bplace_body((int*)shm, row, col, w, off, tmp, nT, NB, E, blockIdx.x);
    } else {
        gemm_body<false>(shm, x, wt1, nullptr, nullptr, nullptr,
                         0.f, Hb, nNodes, blockIdx.x - nT);
    }
}

__global__ __launch_bounds__(256) void bsort_kernel(const int2* __restrict__ tmp,
                                                    const int* __restrict__ start,
                                                    int2* __restrict__ pairs,
                                                    int* __restrict__ rowptr,
                                                    int N, int NB, int E) {
    __shared__ int cntB[RPB];
    __shared__ int cntS[RPB];
    __shared__ int sc[RPB];
    __shared__ int2 outP[SCAP];
    int b = blockIdx.x, t = threadIdx.x;
    int s0 = start[b], s1 = start[b + 1];
    int len = s1 - s0;
    if (len > SCAP) len = SCAP;

    if (t < RPB) cntB[t] = 0;
    __syncthreads();

    int2 p[16];
    int np = 0;
    #pragma unroll
    for (int k = 0; k < 16; ++k) {
        int i = t + k * 256;
        if (i < len) { p[k] = tmp[s0 + i]; ++np; }
    }
    #pragma unroll
    for (int k = 0; k < 16; ++k) {
        if (k >= np) break;
        atomicAdd(&cntB[((unsigned)p[k].x) >> 25], 1);
    }
    __syncthreads();
    int val = (t < RPB) ? cntB[t] : 0;
    if (t < RPB) sc[t] = val;
    __syncthreads();
    #pragma unroll
    for (int o = 1; o < RPB; o <<= 1) {
        int add = (t < RPB && t >= o) ? sc[t - o] : 0;
        __syncthreads();
        if (t < RPB) sc[t] += add;
        __syncthreads();
    }
    if (t < RPB) { int ex = sc[t] - val; cntB[t] = ex; cntS[t] = ex; }
    __syncthreads();
    #pragma unroll
    for (int k = 0; k < 16; ++k) {
        if (k >= np) break;
        int rl = ((unsigned)p[k].x) >> 25;
        int lr = atomicAdd(&cntB[rl], 1);
        outP[lr] = make_int2(p[k].x & 0x1ffffff, p[k].y);
    }
    __syncthreads();
    for (int i = t; i < len; i += 256) pairs[s0 + i] = outP[i];
    int r0 = b * RPB;
    if (t < RPB && r0 + t < N) rowptr[r0 + t] = s0 + cntS[t];
    if (b == NB - 1 && t == 0) rowptr[N] = E;
}

// ---------------------------------------------------------------------------
// CSR SpMM (round-0 proven structure): one wave per row; 4 edge-subgroups x
// 16 lanes (uint4 = 8 feats per lane, MLP-4); shfl_xor reduction.  bf16 out
// cached (re-read); fp32 out NT-stored (never re-read).
// ---------------------------------------------------------------------------
template <bool BF16OUT>
__global__ __launch_bounds__(256) void spmm_csr_kernel(const int* __restrict__ rowptr,
                                                       const int2* __restrict__ pairs,
                                                       const unsigned int* __restrict__ Hb,
                                                       const float* __restrict__ bias,
                                                       void* __restrict__ outv, int N) {
    int r = blockIdx.x * 4 + (threadIdx.x >> 6);
    if (r >= N) return;
    const int l = threadIdx.x & 63;
    const int g = l >> 4, q = l & 15;          // edge subgroup, 8-feat chunk
    const uint4* H4 = (const uint4*)Hb;        // row = 16 uint4

    float acc[8];
    #pragma unroll
    for (int j = 0; j < 8; ++j) acc[j] = 0.f;

    int i = rowptr[r], end = rowptr[r + 1];

    for (; i + 16 <= end; i += 16) {
        int2 p[4];
        uint4 gv[4];
        #pragma unroll
        for (int k = 0; k < 4; ++k) p[k] = pairs[i + 4 * k + g];
        #pragma unroll
        for (int k = 0; k < 4; ++k) gv[k] = H4[(size_t)p[k].x * 16 + q];
        #pragma unroll
        for (int k = 0; k < 4; ++k) {
            float wt = __int_as_float(p[k].y);
            unsigned int uu[4] = {gv[k].x, gv[k].y, gv[k].z, gv[k].w};
            #pragma unroll
            for (int j = 0; j < 4; ++j) {
                acc[2 * j]     = fmaf(wt, __uint_as_float(uu[j] << 16), acc[2 * j]);
                acc[2 * j + 1] = fmaf(wt, __uint_as_float(uu[j] & 0xffff0000u), acc[2 * j + 1]);
            }
        }
    }
    for (; i + 4 <= end; i += 4) {
        int2 p = pairs[i + g];
        uint4 gv = H4[(size_t)p.x * 16 + q];
        float wt = __int_as_float(p.y);
        unsigned int uu[4] = {gv.x, gv.y, gv.z, gv.w};
        #pragma unroll
        for (int j = 0; j < 4; ++j) {
            acc[2 * j]     = fmaf(wt, __uint_as_float(uu[j] << 16), acc[2 * j]);
            acc[2 * j + 1] = fmaf(wt, __uint_as_float(uu[j] & 0xffff0000u), acc[2 * j + 1]);
        }
    }
    if (i < end) {
        int e = i + g;
        int2 p = (e < end) ? pairs[e] : make_int2(0, 0);   // wt=0 for pad lanes
        uint4 gv = H4[(size_t)p.x * 16 + q];
        float wt = __int_as_float(p.y);
        unsigned int uu[4] = {gv.x, gv.y, gv.z, gv.w};
        #pragma unroll
        for (int j = 0; j < 4; ++j) {
            acc[2 * j]     = fmaf(wt, __uint_as_float(uu[j] << 16), acc[2 * j]);
            acc[2 * j + 1] = fmaf(wt, __uint_as_float(uu[j] & 0xffff0000u), acc[2 * j + 1]);
        }
    }

    // reduce the 4 edge-subgroups (lanes q, q+16, q+32, q+48)
    #pragma unroll
    for (int j = 0; j < 8; ++j) {
        acc[j] += __shfl_xor(acc[j], 16, 64);
        acc[j] += __shfl_xor(acc[j], 32, 64);
    }

    if (g == 0) {
        if (bias) {
            float4 b0 = ((const float4*)bias)[q * 2];
            float4 b1 = ((const float4*)bias)[q * 2 + 1];
            acc[0] += b0.x; acc[1] += b0.y; acc[2] += b0.z; acc[3] += b0.w;
            acc[4] += b1.x; acc[5] += b1.y; acc[6] += b1.z; acc[7] += b1.w;
        }
        if (BF16OUT) {
            uint4 pk;
            pk.x = f2bf2(acc[0], acc[1]);
            pk.y = f2bf2(acc[2], acc[3]);
            pk.z = f2bf2(acc[4], acc[5]);
            pk.w = f2bf2(acc[6], acc[7]);
            ((uint4*)outv)[(size_t)r * 16 + q] = pk;           // cached: re-read
        } else {
            f32x4 v0 = (f32x4){acc[0], acc[1], acc[2], acc[3]};
            f32x4 v1 = (f32x4){acc[4], acc[5], acc[6], acc[7]};
            f32x4* O = (f32x4*)outv;
            __builtin_nontemporal_store(v0, &O[(size_t)r * 32 + q * 2]);
            __builtin_nontemporal_store(v1, &O[(size_t)r * 32 + q * 2 + 1]);
        }
    }
}

// ---------------------------------------------------------------------------
// BN batch statistics over packed-bf16 input: per-feature sum and sumsq.
// ---------------------------------------------------------------------------
__global__ __launch_bounds__(256) void bnstats_kernel(const unsigned int* __restrict__ Hu,
                                                      float* __restrict__ sums,
                                                      int nNodes) {
    int u = threadIdx.x & 63;   // uint index: feats 2u, 2u+1
    int g = threadIdx.x >> 6;   // 0..3
    int stride = gridDim.x * 4;
    float s0 = 0.f, s1 = 0.f, q0 = 0.f, q1 = 0.f;
    for (int n = blockIdx.x * 4 + g; n < nNodes; n += stride) {
        unsigned int v = Hu[(size_t)n * FU + u];
        float a = __uint_as_float(v << 16);
        float b = __uint_as_float(v & 0xffff0000u);
        s0 += a; s1 += b;
        q0 = fmaf(a, a, q0); q1 = fmaf(b, b, q1);
    }
    __shared__ float4 red[256];
    red[threadIdx.x] = make_float4(s0, s1, q0, q1);
    __syncthreads();
    if (g == 0) {
        float4 r0 = red[u], r1 = red[64 + u], r2 = red[128 + u], r3 = red[192 + u];
        atomicAdd(&sums[2 * u],           r0.x + r1.x + r2.x + r3.x);
        atomicAdd(&sums[2 * u + 1],       r0.y + r1.y + r2.y + r3.y);
        atomicAdd(&sums[128 + 2 * u],     r0.z + r1.z + r2.z + r3.z);
        atomicAdd(&sums[128 + 2 * u + 1], r0.w + r1.w + r2.w + r3.w);
    }
}

extern "C" void kernel_launch(void* const* d_in, const int* in_sizes, int n_in,
                              void* d_out, int out_size, void* d_ws, size_t ws_size,
                              hipStream_t stream) {
    const float* x    = (const float*)d_in[0];
    const int*   erow = (const int*)d_in[1];
    const int*   ecol = (const int*)d_in[2];
    const float* ew   = (const float*)d_in[3];
    const float* W1   = (const float*)d_in[4];
    // d_in[5] = b1: unused — cancels exactly under BatchNorm mean subtraction.
    const float* W2   = (const float*)d_in[6];
    const float* b2   = (const float*)d_in[7];
    const float* gmm  = (const float*)d_in[8];
    const float* beta = (const float*)d_in[9];
    float* out = (float*)d_out;

    const int N = in_sizes[0] / F;   // 100000
    const int E = in_sizes[1];       // 1600000

    const int NB = (N + RPB - 1) / RPB;     // 782
    const int nT = (E + TILE - 1) / TILE;   // 196

    // ---- workspace carve-up ----
    unsigned int* buf1   = (unsigned int*)d_ws;                   // N*FU bf16 (h1)
    unsigned int* Hb     = buf1 + (size_t)N * FU;                 // N*FU bf16 (h0/h2)
    float*        stats  = (float*)(Hb + (size_t)N * FU);         // 256
    unsigned int* wt1    = (unsigned int*)(stats + 256);          // 8192 (W1 bf16 [f][k])
    unsigned int* wt2    = wt1 + 8192;                            // 8192 (W2 bf16 [f][k])
    int*          rowptr = (int*)(wt2 + 8192);                    // N+2
    int*          start  = rowptr + N + 2;                        // 1028
    int*          total  = start + 1028;                          // 1024
    int*          hist   = total + 1024;                          // nT*NB
    int*          off    = hist + (size_t)nT * NB;                // NB*nT
    int2*         tmp    = (int2*)(off + (size_t)NB * nT);        // E
    int2*         pairs  = tmp + E;                               // E

    const int gemmGrid = (N + 63) / 64;
    const int spmmGrid = (N + 3) / 4;

    hipMemsetAsync(stats, 0, 256 * sizeof(float), stream);

    // ---- fused W pre-pack + histogram ----
    wchisto_kernel<<<nT + 2, 256, 0, stream>>>(W1, W2, wt1, wt2, erow, hist, NB, E);
    btot_kernel<<<NB, 256, 0, stream>>>(hist, total, nT, NB);
    boffs_kernel<<<NB, 1024, 0, stream>>>(hist, total, start, off, nT, NB, E);
    // ---- fused edge placement + layer-1 GEMM (independent) ----
    bpgemm_kernel<<<nT + gemmGrid, 256, 0, stream>>>(erow, ecol, ew, off, tmp,
                                                     x, wt1, Hb, nT, NB, E, N);
    bsort_kernel<<<NB, 256, 0, stream>>>(tmp, start, pairs, rowptr, N, NB, E);

    // Layer 1 aggregate: buf1 = bf16(A @ Hb)
    spmm_csr_kernel<true><<<spmmGrid, 256, 0, stream>>>(rowptr, pairs, Hb,
                                                        nullptr, buf1, N);
    // BN stats (BN-fold happens inside gemm<true>)
    bnstats_kernel<<<400, 256, 0, stream>>>(buf1, stats, N);
    // Layer 2: Hb = bf16(relu(bn(buf1)) @ W2) ; out = A @ Hb + b2 (fp32)
    gemm_kernel<true><<<gemmGrid, 256, 0, stream>>>(buf1, wt2, stats, gmm, beta,
                                                    1.0f / (float)N, Hb, N);
    spmm_csr_kernel<false><<<spmmGrid, 256, 0, stream>>>(rowptr, pairs, Hb,
                                                         b2, out, N);
}